// Round 8
// baseline (236.122 us; speedup 1.0000x reference)
//
#include <hip/hip_runtime.h>

// GCN decoder: z2 = A( relu(A(x)@W1 + b1) )@W2 + b2,  A = D^-1/2 (Adj+I) D^-1/2
// Aggregation at width-128 both layers, CSR gather, hierarchical scan.
// Round 8: scatter writes ONLY esrc (edge weight recomputed in gather from
// L2-resident dinv table) -> halves random write-allocate traffic.

constexpr int F = 128;    // aggregation width
constexpr int HID = 256;  // hidden width

typedef __attribute__((ext_vector_type(8))) short bf16x8;
typedef __attribute__((ext_vector_type(4))) float f32x4;

__device__ inline unsigned short f2bf(float f) {
  unsigned u = __float_as_uint(f);
  u += 0x7fffu + ((u >> 16) & 1u);  // round-to-nearest-even
  return (unsigned short)(u >> 16);
}
__device__ inline float bf2f(unsigned short s) {
  return __uint_as_float(((unsigned)s) << 16);
}

__global__ __launch_bounds__(256) void k_zero_deg(unsigned* deg, int N) {
  int i = blockIdx.x * 256 + threadIdx.x;
  if (i < N) deg[i] = 0u;
}

__global__ __launch_bounds__(256) void k_deg_hist(const int* __restrict__ dst,
                                                  unsigned* deg, int E) {
  int e = blockIdx.x * 256 + threadIdx.x;
  if (e < E) atomicAdd(&deg[dst[e]], 1u);
}

__global__ __launch_bounds__(256) void k_dinv(const unsigned* __restrict__ deg,
                                              float* dinv, int N) {
  int i = blockIdx.x * 256 + threadIdx.x;
  if (i < N) dinv[i] = rsqrtf((float)deg[i] + 1.0f);  // +1 = self-loop
}

// fp32 -> bf16 plane (x table for layer-1 gather)
__global__ __launch_bounds__(256) void k_tobf(const float* __restrict__ in,
                                              unsigned short* __restrict__ outp,
                                              int n4) {
  int i = blockIdx.x * 256 + threadIdx.x;
  if (i >= n4) return;
  float4 v = ((const float4*)in)[i];
  ushort4 o;
  o.x = f2bf(v.x); o.y = f2bf(v.y); o.z = f2bf(v.z); o.w = f2bf(v.w);
  ((ushort4*)outp)[i] = o;
}

// transpose + split W[K][Nn] -> hi/lo [Nn][K] bf16
__global__ __launch_bounds__(256) void k_wsplit(const float* __restrict__ W,
                                                unsigned short* __restrict__ hi,
                                                unsigned short* __restrict__ lo,
                                                int K, int Nn) {
  int idx = blockIdx.x * 256 + threadIdx.x;
  if (idx >= K * Nn) return;
  int k = idx / Nn, n = idx - k * Nn;
  float f = W[idx];
  unsigned short h = f2bf(f);
  unsigned short l = f2bf(f - bf2f(h));
  hi[n * K + k] = h;
  lo[n * K + k] = l;
}

// scan stage 1
__global__ __launch_bounds__(256) void k_scan1(const unsigned* __restrict__ deg,
                                               int* __restrict__ rowptr,
                                               unsigned* __restrict__ bsum, int N) {
  __shared__ unsigned wsum[4];
  int i = blockIdx.x * 256 + threadIdx.x;
  unsigned v = (i < N) ? deg[i] : 0u;
  unsigned sv = v;
#pragma unroll
  for (int off = 1; off < 64; off <<= 1) {
    unsigned t = __shfl_up(sv, off);
    if ((int)(threadIdx.x & 63) >= off) sv += t;
  }
  int w = threadIdx.x >> 6;
  if ((threadIdx.x & 63) == 63) wsum[w] = sv;
  __syncthreads();
  unsigned wpre = 0;
  for (int k = 0; k < w; ++k) wpre += wsum[k];
  unsigned excl = wpre + sv - v;
  if (i < N) rowptr[i] = (int)excl;
  if (threadIdx.x == 255) bsum[blockIdx.x] = excl + v;
}

// scan stage 2
__global__ __launch_bounds__(256) void k_scan2(unsigned* __restrict__ bsum,
                                               int* __restrict__ rowptr, int nb, int N) {
  __shared__ unsigned wsum[4];
  __shared__ unsigned carry;
  if (threadIdx.x == 0) carry = 0u;
  __syncthreads();
  for (int c0 = 0; c0 < nb; c0 += 256) {
    int i = c0 + threadIdx.x;
    unsigned v = (i < nb) ? bsum[i] : 0u;
    unsigned sv = v;
#pragma unroll
    for (int off = 1; off < 64; off <<= 1) {
      unsigned t = __shfl_up(sv, off);
      if ((int)(threadIdx.x & 63) >= off) sv += t;
    }
    int w = threadIdx.x >> 6;
    if ((threadIdx.x & 63) == 63) wsum[w] = sv;
    __syncthreads();
    unsigned wpre = 0;
    for (int k = 0; k < w; ++k) wpre += wsum[k];
    unsigned excl = carry + wpre + sv - v;
    if (i < nb) bsum[i] = excl;
    __syncthreads();
    if (threadIdx.x == 255) carry = excl + v;
    __syncthreads();
  }
  if (threadIdx.x == 0) rowptr[N] = (int)carry;
}

// scan stage 3: add block offsets; zero the scatter cursor
__global__ __launch_bounds__(256) void k_scan3(const unsigned* __restrict__ bsum,
                                               int* __restrict__ rowptr,
                                               unsigned* __restrict__ cursor, int N) {
  int i = blockIdx.x * 256 + threadIdx.x;
  if (i < N) {
    rowptr[i] += (int)bsum[blockIdx.x];
    cursor[i] = 0u;
  }
}

// Bucket edges by dst: single 4B random write per edge (esrc only)
__global__ __launch_bounds__(256) void k_scatter(const int* __restrict__ src,
                                                 const int* __restrict__ dst,
                                                 const int* __restrict__ rowptr,
                                                 unsigned* __restrict__ cursor,
                                                 int* __restrict__ esrc, int E) {
  int e = blockIdx.x * 256 + threadIdx.x;
  if (e >= E) return;
  int s = src[e], d = dst[e];
  unsigned pos = (unsigned)rowptr[d] + atomicAdd(&cursor[d], 1u);
  esrc[pos] = s;
}

// Layer-1 agg: gather bf16 x rows, w = dinv[s]*dinv[node] on the fly,
// self-term fp32, write split hi/lo planes.
__global__ __launch_bounds__(256) void k_agg_bf(const int* __restrict__ rowptr,
                                                const int* __restrict__ esrc,
                                                const float* __restrict__ dinv,
                                                const float* __restrict__ xf,
                                                const unsigned short* __restrict__ xb,
                                                unsigned short* __restrict__ outh,
                                                unsigned short* __restrict__ outl,
                                                int N) {
  int node = blockIdx.x * 4 + (threadIdx.x >> 6);
  int lane = threadIdx.x & 63;
  if (node >= N) return;
  float di = dinv[node];
  float w0 = di * di;
  float2 acc = ((const float2*)(xf + (size_t)node * F))[lane];
  acc.x *= w0; acc.y *= w0;
  int beg = rowptr[node], end = rowptr[node + 1];
  for (int b = beg; b < end; b += 64) {
    int n = min(64, end - b);
    int s = 0;
    float w = 0.f;
    if (lane < n) {
      s = esrc[b + lane];
      w = dinv[s] * di;
    }
    int t = 0;
    for (; t + 3 < n; t += 4) {
      int s0 = __shfl(s, t), s1 = __shfl(s, t + 1);
      int s2 = __shfl(s, t + 2), s3 = __shfl(s, t + 3);
      float wa = __shfl(w, t), wb = __shfl(w, t + 1);
      float wc = __shfl(w, t + 2), wd = __shfl(w, t + 3);
      ushort2 v0 = ((const ushort2*)(xb + (size_t)s0 * F))[lane];
      ushort2 v1 = ((const ushort2*)(xb + (size_t)s1 * F))[lane];
      ushort2 v2 = ((const ushort2*)(xb + (size_t)s2 * F))[lane];
      ushort2 v3 = ((const ushort2*)(xb + (size_t)s3 * F))[lane];
      acc.x += bf2f(v0.x) * wa; acc.y += bf2f(v0.y) * wa;
      acc.x += bf2f(v1.x) * wb; acc.y += bf2f(v1.y) * wb;
      acc.x += bf2f(v2.x) * wc; acc.y += bf2f(v2.y) * wc;
      acc.x += bf2f(v3.x) * wd; acc.y += bf2f(v3.y) * wd;
    }
    for (; t < n; ++t) {
      int s0 = __shfl(s, t);
      float wa = __shfl(w, t);
      ushort2 v0 = ((const ushort2*)(xb + (size_t)s0 * F))[lane];
      acc.x += bf2f(v0.x) * wa; acc.y += bf2f(v0.y) * wa;
    }
  }
  unsigned short hx = f2bf(acc.x), hy = f2bf(acc.y);
  unsigned short lx = f2bf(acc.x - bf2f(hx)), ly = f2bf(acc.y - bf2f(hy));
  ushort2 hv; hv.x = hx; hv.y = hy;
  ushort2 lv; lv.x = lx; lv.y = ly;
  ((ushort2*)(outh + (size_t)node * F))[lane] = hv;
  ((ushort2*)(outl + (size_t)node * F))[lane] = lv;
}

// Layer-2 agg: gather bf16 h2 rows, w on the fly, + bias -> fp32 out (final)
__global__ __launch_bounds__(256) void k_agg_out(const int* __restrict__ rowptr,
                                                 const int* __restrict__ esrc,
                                                 const float* __restrict__ dinv,
                                                 const unsigned short* __restrict__ hb,
                                                 const float* __restrict__ bias,
                                                 float* __restrict__ outp, int N) {
  int node = blockIdx.x * 4 + (threadIdx.x >> 6);
  int lane = threadIdx.x & 63;
  if (node >= N) return;
  float di = dinv[node];
  float w0 = di * di;
  ushort2 sv2 = ((const ushort2*)(hb + (size_t)node * F))[lane];
  float2 bb = ((const float2*)bias)[lane];
  float2 acc;
  acc.x = bf2f(sv2.x) * w0 + bb.x;
  acc.y = bf2f(sv2.y) * w0 + bb.y;
  int beg = rowptr[node], end = rowptr[node + 1];
  for (int b = beg; b < end; b += 64) {
    int n = min(64, end - b);
    int s = 0;
    float w = 0.f;
    if (lane < n) {
      s = esrc[b + lane];
      w = dinv[s] * di;
    }
    int t = 0;
    for (; t + 3 < n; t += 4) {
      int s0 = __shfl(s, t), s1 = __shfl(s, t + 1);
      int s2 = __shfl(s, t + 2), s3 = __shfl(s, t + 3);
      float wa = __shfl(w, t), wb = __shfl(w, t + 1);
      float wc = __shfl(w, t + 2), wd = __shfl(w, t + 3);
      ushort2 v0 = ((const ushort2*)(hb + (size_t)s0 * F))[lane];
      ushort2 v1 = ((const ushort2*)(hb + (size_t)s1 * F))[lane];
      ushort2 v2 = ((const ushort2*)(hb + (size_t)s2 * F))[lane];
      ushort2 v3 = ((const ushort2*)(hb + (size_t)s3 * F))[lane];
      acc.x += bf2f(v0.x) * wa; acc.y += bf2f(v0.y) * wa;
      acc.x += bf2f(v1.x) * wb; acc.y += bf2f(v1.y) * wb;
      acc.x += bf2f(v2.x) * wc; acc.y += bf2f(v2.y) * wc;
      acc.x += bf2f(v3.x) * wd; acc.y += bf2f(v3.y) * wd;
    }
    for (; t < n; ++t) {
      int s0 = __shfl(s, t);
      float wa = __shfl(w, t);
      ushort2 v0 = ((const ushort2*)(hb + (size_t)s0 * F))[lane];
      acc.x += bf2f(v0.x) * wa; acc.y += bf2f(v0.y) * wa;
    }
  }
  ((float2*)(outp + (size_t)node * F))[lane] = acc;
}

// GEMM1: z1(bf16) = relu( (Ah+Al)[M,128] @ (W1h+W1l)^T[256,128] + b1 )
__global__ __launch_bounds__(256) void k_gemm1(const unsigned short* __restrict__ Ah,
                                               const unsigned short* __restrict__ Al,
                                               const unsigned short* __restrict__ Bh,
                                               const unsigned short* __restrict__ Bl,
                                               const float* __restrict__ bias,
                                               unsigned short* __restrict__ Cbf,
                                               int M) {
  __shared__ unsigned short AhL[64 * 128];
  __shared__ unsigned short AlL[64 * 128];
  int tid = threadIdx.x;
  int lane = tid & 63, wid = tid >> 6;
  int row0 = blockIdx.x * 64;

#pragma unroll
  for (int i = 0; i < 4; ++i) {
    int g = i * 256 + tid;
    int r = g >> 4, gi = g & 15;
    int o = r * 128 + (gi ^ (r & 7)) * 8;
    size_t go = (size_t)(row0 + r) * 128 + gi * 8;
    *(bf16x8*)&AhL[o] = *(const bf16x8*)&Ah[go];
    *(bf16x8*)&AlL[o] = *(const bf16x8*)&Al[go];
  }
  __syncthreads();

  f32x4 acc[4][4] = {};
#pragma unroll
  for (int ks = 0; ks < 4; ++ks) {
    bf16x8 ah[4], al[4], bh[4], bl[4];
#pragma unroll
    for (int mf = 0; mf < 4; ++mf) {
      int r = mf * 16 + (lane & 15);
      int g = ks * 4 + (lane >> 4);
      int o = r * 128 + (g ^ (r & 7)) * 8;
      ah[mf] = *(const bf16x8*)&AhL[o];
      al[mf] = *(const bf16x8*)&AlL[o];
    }
#pragma unroll
    for (int nf = 0; nf < 4; ++nf) {
      int c = wid * 64 + nf * 16 + (lane & 15);
      size_t o = (size_t)c * 128 + ks * 32 + (lane >> 4) * 8;
      bh[nf] = *(const bf16x8*)&Bh[o];
      bl[nf] = *(const bf16x8*)&Bl[o];
    }
#pragma unroll
    for (int mf = 0; mf < 4; ++mf)
#pragma unroll
      for (int nf = 0; nf < 4; ++nf) {
        acc[mf][nf] = __builtin_amdgcn_mfma_f32_16x16x32_bf16(
            ah[mf], bh[nf], acc[mf][nf], 0, 0, 0);
        acc[mf][nf] = __builtin_amdgcn_mfma_f32_16x16x32_bf16(
            ah[mf], bl[nf], acc[mf][nf], 0, 0, 0);
        acc[mf][nf] = __builtin_amdgcn_mfma_f32_16x16x32_bf16(
            al[mf], bh[nf], acc[mf][nf], 0, 0, 0);
      }
  }

#pragma unroll
  for (int mf = 0; mf < 4; ++mf) {
    int r0 = row0 + mf * 16 + (lane >> 4) * 4;
#pragma unroll
    for (int nf = 0; nf < 4; ++nf) {
      int c = wid * 64 + nf * 16 + (lane & 15);
      float bv = bias[c];
#pragma unroll
      for (int r = 0; r < 4; ++r) {
        if (r0 + r < M) {
          float v = fmaxf(acc[mf][nf][r] + bv, 0.f);
          Cbf[(size_t)(r0 + r) * HID + c] = f2bf(v);
        }
      }
    }
  }
}

// GEMM2: h2(bf16) = Z(bf16)[M,256] @ (W2h+W2l)^T[128,256]   (2-term split)
__global__ __launch_bounds__(256) void k_gemm2(const unsigned short* __restrict__ Z,
                                               const unsigned short* __restrict__ Bh,
                                               const unsigned short* __restrict__ Bl,
                                               unsigned short* __restrict__ Cbf,
                                               int M) {
  __shared__ unsigned short ZL[64 * 256];
  int tid = threadIdx.x;
  int lane = tid & 63, wid = tid >> 6;
  int row0 = blockIdx.x * 64;

#pragma unroll
  for (int i = 0; i < 8; ++i) {
    int g = i * 256 + tid;
    int r = g >> 5, gi = g & 31;
    int o = r * 256 + (gi ^ (r & 7)) * 8;
    size_t go = (size_t)(row0 + r) * 256 + gi * 8;
    *(bf16x8*)&ZL[o] = *(const bf16x8*)&Z[go];
  }
  __syncthreads();

  f32x4 acc[4][2] = {};
#pragma unroll
  for (int ks = 0; ks < 8; ++ks) {
    bf16x8 ah[4], bh[2], bl[2];
#pragma unroll
    for (int mf = 0; mf < 4; ++mf) {
      int r = mf * 16 + (lane & 15);
      int g = ks * 4 + (lane >> 4);
      int o = r * 256 + (g ^ (r & 7)) * 8;
      ah[mf] = *(const bf16x8*)&ZL[o];
    }
#pragma unroll
    for (int nf = 0; nf < 2; ++nf) {
      int c = wid * 32 + nf * 16 + (lane & 15);
      size_t o = (size_t)c * 256 + ks * 32 + (lane >> 4) * 8;
      bh[nf] = *(const bf16x8*)&Bh[o];
      bl[nf] = *(const bf16x8*)&Bl[o];
    }
#pragma unroll
    for (int mf = 0; mf < 4; ++mf)
#pragma unroll
      for (int nf = 0; nf < 2; ++nf) {
        acc[mf][nf] = __builtin_amdgcn_mfma_f32_16x16x32_bf16(
            ah[mf], bh[nf], acc[mf][nf], 0, 0, 0);
        acc[mf][nf] = __builtin_amdgcn_mfma_f32_16x16x32_bf16(
            ah[mf], bl[nf], acc[mf][nf], 0, 0, 0);
      }
  }

#pragma unroll
  for (int mf = 0; mf < 4; ++mf) {
    int r0 = row0 + mf * 16 + (lane >> 4) * 4;
#pragma unroll
    for (int nf = 0; nf < 2; ++nf) {
      int c = wid * 32 + nf * 16 + (lane & 15);
#pragma unroll
      for (int r = 0; r < 4; ++r)
        if (r0 + r < M) Cbf[(size_t)(r0 + r) * F + c] = f2bf(acc[mf][nf][r]);
    }
  }
}

extern "C" void kernel_launch(void* const* d_in, const int* in_sizes, int n_in,
                              void* d_out, int out_size, void* d_ws, size_t ws_size,
                              hipStream_t stream) {
  const float* x = (const float*)d_in[0];
  const int* ei = (const int*)d_in[1];
  const float* W1 = (const float*)d_in[2];
  const float* b1 = (const float*)d_in[3];
  const float* W2 = (const float*)d_in[4];
  const float* b2 = (const float*)d_in[5];
  float* out = (float*)d_out;

  int N = in_sizes[0] / F;  // 50000
  int E = in_sizes[1] / 2;  // 800000
  const int* src = ei;
  const int* dst = ei + E;

  // workspace layout (byte-based, 256B aligned chunks)
  char* ws = (char*)d_ws;
  size_t off = 0;
  auto allocB = [&](size_t bytes) {
    void* p = ws + off;
    off += ((bytes + 255) & ~(size_t)255);
    return p;
  };
  unsigned* deg = (unsigned*)allocB((size_t)N * 4);  // histogram, then cursor
  float* dinv = (float*)allocB((size_t)N * 4);
  int* rowptr = (int*)allocB(((size_t)N + 1) * 4);
  unsigned* bsum = (unsigned*)allocB(1024);
  int* esrc = (int*)allocB((size_t)E * 4);
  unsigned short* xb = (unsigned short*)allocB((size_t)N * F * 2);  // x bf16 table
  // +64 row padding so tail-block LDS staging reads stay in-bounds
  unsigned short* aggh = (unsigned short*)allocB((size_t)(N + 64) * F * 2);
  unsigned short* aggl = (unsigned short*)allocB((size_t)(N + 64) * F * 2);
  unsigned short* z1h = (unsigned short*)allocB((size_t)(N + 64) * HID * 2);
  unsigned short* w1th = (unsigned short*)allocB((size_t)F * HID * 2);
  unsigned short* w1tl = (unsigned short*)allocB((size_t)F * HID * 2);
  unsigned short* w2th = (unsigned short*)allocB((size_t)HID * F * 2);
  unsigned short* w2tl = (unsigned short*)allocB((size_t)HID * F * 2);
  // h2 bf16 (12.8MB) reuses the aggh plane (dead after GEMM1)
  unsigned short* h2b = aggh;

  int nbN = (N + 255) / 256;
  int nbE = (E + 255) / 256;
  int nbW = (F * HID + 255) / 256;
  int nbX = (N * F / 4 + 255) / 256;

  k_wsplit<<<nbW, 256, 0, stream>>>(W1, w1th, w1tl, F, HID);  // [256][128]
  k_wsplit<<<nbW, 256, 0, stream>>>(W2, w2th, w2tl, HID, F);  // [128][256]
  k_tobf<<<nbX, 256, 0, stream>>>(x, xb, N * F / 4);

  k_zero_deg<<<nbN, 256, 0, stream>>>(deg, N);
  k_deg_hist<<<nbE, 256, 0, stream>>>(dst, deg, E);
  k_dinv<<<nbN, 256, 0, stream>>>(deg, dinv, N);
  k_scan1<<<nbN, 256, 0, stream>>>(deg, rowptr, bsum, N);
  k_scan2<<<1, 256, 0, stream>>>(bsum, rowptr, nbN, N);
  k_scan3<<<nbN, 256, 0, stream>>>(bsum, rowptr, deg, N);
  k_scatter<<<nbE, 256, 0, stream>>>(src, dst, rowptr, deg, esrc, E);

  int nbAgg = (N + 3) / 4;
  int mb = (N + 63) / 64;

  // layer 1: agg(hi/lo) = A x  (bf16 gather) ; z1(bf16) = relu(agg @ W1 + b1)
  k_agg_bf<<<nbAgg, 256, 0, stream>>>(rowptr, esrc, dinv, x, xb, aggh, aggl, N);
  k_gemm1<<<mb, 256, 0, stream>>>(aggh, aggl, w1th, w1tl, b1, z1h, N);

  // layer 2: h2(bf16) = z1 @ W2 ; out = b2 + A h2  (bf16 gather)
  k_gemm2<<<mb, 256, 0, stream>>>(z1h, w2th, w2tl, h2b, N);
  k_agg_out<<<nbAgg, 256, 0, stream>>>(rowptr, esrc, dinv, h2b, b2, out, N);
}

// Round 9
// 195.406 us; speedup vs baseline: 1.2084x; 1.2084x over previous
//
#include <hip/hip_runtime.h>

// GCN decoder: z2 = A( relu(A(x)@W1 + b1) )@W2 + b2,  A = D^-1/2 (Adj+I) D^-1/2
// Aggregation at width-128 both layers, CSR gather.
// Round 9: CSR built via bucketed counting sort (256-node dst buckets).
// All per-edge atomics are LDS atomics; global atomics only per (block,bucket).
// Requires N < 65536 (src packed in 16 bits) -- N = 50000 here.

constexpr int F = 128;    // aggregation width
constexpr int HID = 256;  // hidden width
constexpr int ECHUNK = 8192;  // edges per binning block

typedef __attribute__((ext_vector_type(8))) short bf16x8;
typedef __attribute__((ext_vector_type(4))) float f32x4;

__device__ inline unsigned short f2bf(float f) {
  unsigned u = __float_as_uint(f);
  u += 0x7fffu + ((u >> 16) & 1u);  // round-to-nearest-even
  return (unsigned short)(u >> 16);
}
__device__ inline float bf2f(unsigned short s) {
  return __uint_as_float(((unsigned)s) << 16);
}

__global__ __launch_bounds__(256) void k_bzero(unsigned* bcnt) {
  bcnt[threadIdx.x] = 0u;
}

// binning pass 1: per-block LDS histogram of dst buckets -> global bucket counts
__global__ __launch_bounds__(256) void k_binc(const int* __restrict__ dst,
                                              unsigned* __restrict__ bcnt, int E) {
  __shared__ unsigned hist[256];
  int tid = threadIdx.x;
  hist[tid] = 0u;
  __syncthreads();
  int i0 = blockIdx.x * ECHUNK;
  int i1 = min(i0 + ECHUNK, E);
  for (int i = i0 + tid; i < i1; i += 256)
    atomicAdd(&hist[((unsigned)dst[i]) >> 8], 1u);
  __syncthreads();
  unsigned c = hist[tid];
  if (c) atomicAdd(&bcnt[tid], c);
}

// scan bucket counts -> bbase[P+1], init bcur, write rowptr[N]=E
__global__ __launch_bounds__(256) void k_bscan(const unsigned* __restrict__ bcnt,
                                               unsigned* __restrict__ bbase,
                                               unsigned* __restrict__ bcur,
                                               int* __restrict__ rowptr,
                                               int P, int N, int E) {
  __shared__ unsigned wsum[4];
  int tid = threadIdx.x;
  unsigned v = (tid < P) ? bcnt[tid] : 0u;
  unsigned sv = v;
#pragma unroll
  for (int off = 1; off < 64; off <<= 1) {
    unsigned t = __shfl_up(sv, off);
    if ((tid & 63) >= off) sv += t;
  }
  int w = tid >> 6;
  if ((tid & 63) == 63) wsum[w] = sv;
  __syncthreads();
  unsigned wpre = 0;
  for (int k = 0; k < w; ++k) wpre += wsum[k];
  unsigned excl = wpre + sv - v;
  if (tid < P) {
    bbase[tid] = excl;
    bcur[tid] = excl;
  }
  if (tid == P - 1) bbase[P] = excl + v;
  if (tid == 0) rowptr[N] = E;
}

// binning pass 2: reserve per-(block,bucket) ranges, write packed edges
// packed = src | (dst&255)<<16
__global__ __launch_bounds__(256) void k_binscat(const int* __restrict__ src,
                                                 const int* __restrict__ dst,
                                                 unsigned* __restrict__ bcur,
                                                 unsigned* __restrict__ packed, int E) {
  __shared__ unsigned hist[256];
  __shared__ unsigned basel[256];
  int tid = threadIdx.x;
  hist[tid] = 0u;
  __syncthreads();
  int i0 = blockIdx.x * ECHUNK;
  int i1 = min(i0 + ECHUNK, E);
  for (int i = i0 + tid; i < i1; i += 256)
    atomicAdd(&hist[((unsigned)dst[i]) >> 8], 1u);
  __syncthreads();
  unsigned c = hist[tid];
  if (c) basel[tid] = atomicAdd(&bcur[tid], c);
  __syncthreads();
  hist[tid] = 0u;  // reuse as local cursor
  __syncthreads();
  for (int i = i0 + tid; i < i1; i += 256) {
    unsigned d = (unsigned)dst[i];
    unsigned b = d >> 8;
    unsigned pos = basel[b] + atomicAdd(&hist[b], 1u);
    packed[pos] = ((unsigned)src[i]) | ((d & 255u) << 16);
  }
}

// per-bucket CSR finalize: deg, rowptr (coalesced), esrc (LDS-cursor scatter
// into the bucket's contiguous window)
__global__ __launch_bounds__(256) void k_bcsr(const unsigned* __restrict__ packed,
                                              const unsigned* __restrict__ bbase,
                                              unsigned* __restrict__ deg,
                                              int* __restrict__ rowptr,
                                              int* __restrict__ esrc, int N) {
  __shared__ unsigned hist[256];
  __shared__ unsigned rowloc[256];
  __shared__ unsigned cur[256];
  __shared__ unsigned wsum[4];
  int tid = threadIdx.x, b = blockIdx.x;
  int e0 = (int)bbase[b], e1 = (int)bbase[b + 1];
  hist[tid] = 0u;
  __syncthreads();
  for (int i = e0 + tid; i < e1; i += 256)
    atomicAdd(&hist[packed[i] >> 16], 1u);
  __syncthreads();
  unsigned v = hist[tid];
  unsigned sv = v;
#pragma unroll
  for (int off = 1; off < 64; off <<= 1) {
    unsigned t = __shfl_up(sv, off);
    if ((tid & 63) >= off) sv += t;
  }
  int w = tid >> 6;
  if ((tid & 63) == 63) wsum[w] = sv;
  __syncthreads();
  unsigned wpre = 0;
  for (int k = 0; k < w; ++k) wpre += wsum[k];
  unsigned excl = wpre + sv - v;
  int node = b * 256 + tid;
  if (node < N) {
    deg[node] = v;
    rowptr[node] = e0 + (int)excl;
  }
  rowloc[tid] = (unsigned)e0 + excl;
  cur[tid] = 0u;
  __syncthreads();
  for (int i = e0 + tid; i < e1; i += 256) {
    unsigned pk = packed[i];
    unsigned dl = pk >> 16;
    unsigned pos = rowloc[dl] + atomicAdd(&cur[dl], 1u);
    esrc[pos] = (int)(pk & 0xffffu);
  }
}

__global__ __launch_bounds__(256) void k_dinv(const unsigned* __restrict__ deg,
                                              float* dinv, int N) {
  int i = blockIdx.x * 256 + threadIdx.x;
  if (i < N) dinv[i] = rsqrtf((float)deg[i] + 1.0f);  // +1 = self-loop
}

// fp32 -> bf16 plane (x table for layer-1 gather)
__global__ __launch_bounds__(256) void k_tobf(const float* __restrict__ in,
                                              unsigned short* __restrict__ outp,
                                              int n4) {
  int i = blockIdx.x * 256 + threadIdx.x;
  if (i >= n4) return;
  float4 v = ((const float4*)in)[i];
  ushort4 o;
  o.x = f2bf(v.x); o.y = f2bf(v.y); o.z = f2bf(v.z); o.w = f2bf(v.w);
  ((ushort4*)outp)[i] = o;
}

// transpose + split W[K][Nn] -> hi/lo [Nn][K] bf16
__global__ __launch_bounds__(256) void k_wsplit(const float* __restrict__ W,
                                                unsigned short* __restrict__ hi,
                                                unsigned short* __restrict__ lo,
                                                int K, int Nn) {
  int idx = blockIdx.x * 256 + threadIdx.x;
  if (idx >= K * Nn) return;
  int k = idx / Nn, n = idx - k * Nn;
  float f = W[idx];
  unsigned short h = f2bf(f);
  unsigned short l = f2bf(f - bf2f(h));
  hi[n * K + k] = h;
  lo[n * K + k] = l;
}

// Layer-1 agg: gather bf16 x rows, w = dinv[s]*dinv[node] on the fly,
// self-term fp32, write split hi/lo planes.
__global__ __launch_bounds__(256) void k_agg_bf(const int* __restrict__ rowptr,
                                                const int* __restrict__ esrc,
                                                const float* __restrict__ dinv,
                                                const float* __restrict__ xf,
                                                const unsigned short* __restrict__ xb,
                                                unsigned short* __restrict__ outh,
                                                unsigned short* __restrict__ outl,
                                                int N) {
  int node = blockIdx.x * 4 + (threadIdx.x >> 6);
  int lane = threadIdx.x & 63;
  if (node >= N) return;
  float di = dinv[node];
  float w0 = di * di;
  float2 acc = ((const float2*)(xf + (size_t)node * F))[lane];
  acc.x *= w0; acc.y *= w0;
  int beg = rowptr[node], end = rowptr[node + 1];
  for (int b = beg; b < end; b += 64) {
    int n = min(64, end - b);
    int s = 0;
    float w = 0.f;
    if (lane < n) {
      s = esrc[b + lane];
      w = dinv[s] * di;
    }
    int t = 0;
    for (; t + 3 < n; t += 4) {
      int s0 = __shfl(s, t), s1 = __shfl(s, t + 1);
      int s2 = __shfl(s, t + 2), s3 = __shfl(s, t + 3);
      float wa = __shfl(w, t), wb = __shfl(w, t + 1);
      float wc = __shfl(w, t + 2), wd = __shfl(w, t + 3);
      ushort2 v0 = ((const ushort2*)(xb + (size_t)s0 * F))[lane];
      ushort2 v1 = ((const ushort2*)(xb + (size_t)s1 * F))[lane];
      ushort2 v2 = ((const ushort2*)(xb + (size_t)s2 * F))[lane];
      ushort2 v3 = ((const ushort2*)(xb + (size_t)s3 * F))[lane];
      acc.x += bf2f(v0.x) * wa; acc.y += bf2f(v0.y) * wa;
      acc.x += bf2f(v1.x) * wb; acc.y += bf2f(v1.y) * wb;
      acc.x += bf2f(v2.x) * wc; acc.y += bf2f(v2.y) * wc;
      acc.x += bf2f(v3.x) * wd; acc.y += bf2f(v3.y) * wd;
    }
    for (; t < n; ++t) {
      int s0 = __shfl(s, t);
      float wa = __shfl(w, t);
      ushort2 v0 = ((const ushort2*)(xb + (size_t)s0 * F))[lane];
      acc.x += bf2f(v0.x) * wa; acc.y += bf2f(v0.y) * wa;
    }
  }
  unsigned short hx = f2bf(acc.x), hy = f2bf(acc.y);
  unsigned short lx = f2bf(acc.x - bf2f(hx)), ly = f2bf(acc.y - bf2f(hy));
  ushort2 hv; hv.x = hx; hv.y = hy;
  ushort2 lv; lv.x = lx; lv.y = ly;
  ((ushort2*)(outh + (size_t)node * F))[lane] = hv;
  ((ushort2*)(outl + (size_t)node * F))[lane] = lv;
}

// Layer-2 agg: gather bf16 h2 rows, w on the fly, + bias -> fp32 out (final)
__global__ __launch_bounds__(256) void k_agg_out(const int* __restrict__ rowptr,
                                                 const int* __restrict__ esrc,
                                                 const float* __restrict__ dinv,
                                                 const unsigned short* __restrict__ hb,
                                                 const float* __restrict__ bias,
                                                 float* __restrict__ outp, int N) {
  int node = blockIdx.x * 4 + (threadIdx.x >> 6);
  int lane = threadIdx.x & 63;
  if (node >= N) return;
  float di = dinv[node];
  float w0 = di * di;
  ushort2 sv2 = ((const ushort2*)(hb + (size_t)node * F))[lane];
  float2 bb = ((const float2*)bias)[lane];
  float2 acc;
  acc.x = bf2f(sv2.x) * w0 + bb.x;
  acc.y = bf2f(sv2.y) * w0 + bb.y;
  int beg = rowptr[node], end = rowptr[node + 1];
  for (int b = beg; b < end; b += 64) {
    int n = min(64, end - b);
    int s = 0;
    float w = 0.f;
    if (lane < n) {
      s = esrc[b + lane];
      w = dinv[s] * di;
    }
    int t = 0;
    for (; t + 3 < n; t += 4) {
      int s0 = __shfl(s, t), s1 = __shfl(s, t + 1);
      int s2 = __shfl(s, t + 2), s3 = __shfl(s, t + 3);
      float wa = __shfl(w, t), wb = __shfl(w, t + 1);
      float wc = __shfl(w, t + 2), wd = __shfl(w, t + 3);
      ushort2 v0 = ((const ushort2*)(hb + (size_t)s0 * F))[lane];
      ushort2 v1 = ((const ushort2*)(hb + (size_t)s1 * F))[lane];
      ushort2 v2 = ((const ushort2*)(hb + (size_t)s2 * F))[lane];
      ushort2 v3 = ((const ushort2*)(hb + (size_t)s3 * F))[lane];
      acc.x += bf2f(v0.x) * wa; acc.y += bf2f(v0.y) * wa;
      acc.x += bf2f(v1.x) * wb; acc.y += bf2f(v1.y) * wb;
      acc.x += bf2f(v2.x) * wc; acc.y += bf2f(v2.y) * wc;
      acc.x += bf2f(v3.x) * wd; acc.y += bf2f(v3.y) * wd;
    }
    for (; t < n; ++t) {
      int s0 = __shfl(s, t);
      float wa = __shfl(w, t);
      ushort2 v0 = ((const ushort2*)(hb + (size_t)s0 * F))[lane];
      acc.x += bf2f(v0.x) * wa; acc.y += bf2f(v0.y) * wa;
    }
  }
  ((float2*)(outp + (size_t)node * F))[lane] = acc;
}

// GEMM1: z1(bf16) = relu( (Ah+Al)[M,128] @ (W1h+W1l)^T[256,128] + b1 )
__global__ __launch_bounds__(256) void k_gemm1(const unsigned short* __restrict__ Ah,
                                               const unsigned short* __restrict__ Al,
                                               const unsigned short* __restrict__ Bh,
                                               const unsigned short* __restrict__ Bl,
                                               const float* __restrict__ bias,
                                               unsigned short* __restrict__ Cbf,
                                               int M) {
  __shared__ unsigned short AhL[64 * 128];
  __shared__ unsigned short AlL[64 * 128];
  int tid = threadIdx.x;
  int lane = tid & 63, wid = tid >> 6;
  int row0 = blockIdx.x * 64;

#pragma unroll
  for (int i = 0; i < 4; ++i) {
    int g = i * 256 + tid;
    int r = g >> 4, gi = g & 15;
    int o = r * 128 + (gi ^ (r & 7)) * 8;
    size_t go = (size_t)(row0 + r) * 128 + gi * 8;
    *(bf16x8*)&AhL[o] = *(const bf16x8*)&Ah[go];
    *(bf16x8*)&AlL[o] = *(const bf16x8*)&Al[go];
  }
  __syncthreads();

  f32x4 acc[4][4] = {};
#pragma unroll
  for (int ks = 0; ks < 4; ++ks) {
    bf16x8 ah[4], al[4], bh[4], bl[4];
#pragma unroll
    for (int mf = 0; mf < 4; ++mf) {
      int r = mf * 16 + (lane & 15);
      int g = ks * 4 + (lane >> 4);
      int o = r * 128 + (g ^ (r & 7)) * 8;
      ah[mf] = *(const bf16x8*)&AhL[o];
      al[mf] = *(const bf16x8*)&AlL[o];
    }
#pragma unroll
    for (int nf = 0; nf < 4; ++nf) {
      int c = wid * 64 + nf * 16 + (lane & 15);
      size_t o = (size_t)c * 128 + ks * 32 + (lane >> 4) * 8;
      bh[nf] = *(const bf16x8*)&Bh[o];
      bl[nf] = *(const bf16x8*)&Bl[o];
    }
#pragma unroll
    for (int mf = 0; mf < 4; ++mf)
#pragma unroll
      for (int nf = 0; nf < 4; ++nf) {
        acc[mf][nf] = __builtin_amdgcn_mfma_f32_16x16x32_bf16(
            ah[mf], bh[nf], acc[mf][nf], 0, 0, 0);
        acc[mf][nf] = __builtin_amdgcn_mfma_f32_16x16x32_bf16(
            ah[mf], bl[nf], acc[mf][nf], 0, 0, 0);
        acc[mf][nf] = __builtin_amdgcn_mfma_f32_16x16x32_bf16(
            al[mf], bh[nf], acc[mf][nf], 0, 0, 0);
      }
  }

#pragma unroll
  for (int mf = 0; mf < 4; ++mf) {
    int r0 = row0 + mf * 16 + (lane >> 4) * 4;
#pragma unroll
    for (int nf = 0; nf < 4; ++nf) {
      int c = wid * 64 + nf * 16 + (lane & 15);
      float bv = bias[c];
#pragma unroll
      for (int r = 0; r < 4; ++r) {
        if (r0 + r < M) {
          float v = fmaxf(acc[mf][nf][r] + bv, 0.f);
          Cbf[(size_t)(r0 + r) * HID + c] = f2bf(v);
        }
      }
    }
  }
}

// GEMM2: h2(bf16) = Z(bf16)[M,256] @ (W2h+W2l)^T[128,256]   (2-term split)
__global__ __launch_bounds__(256) void k_gemm2(const unsigned short* __restrict__ Z,
                                               const unsigned short* __restrict__ Bh,
                                               const unsigned short* __restrict__ Bl,
                                               unsigned short* __restrict__ Cbf,
                                               int M) {
  __shared__ unsigned short ZL[64 * 256];
  int tid = threadIdx.x;
  int lane = tid & 63, wid = tid >> 6;
  int row0 = blockIdx.x * 64;

#pragma unroll
  for (int i = 0; i < 8; ++i) {
    int g = i * 256 + tid;
    int r = g >> 5, gi = g & 31;
    int o = r * 256 + (gi ^ (r & 7)) * 8;
    size_t go = (size_t)(row0 + r) * 256 + gi * 8;
    *(bf16x8*)&ZL[o] = *(const bf16x8*)&Z[go];
  }
  __syncthreads();

  f32x4 acc[4][2] = {};
#pragma unroll
  for (int ks = 0; ks < 8; ++ks) {
    bf16x8 ah[4], bh[2], bl[2];
#pragma unroll
    for (int mf = 0; mf < 4; ++mf) {
      int r = mf * 16 + (lane & 15);
      int g = ks * 4 + (lane >> 4);
      int o = r * 256 + (g ^ (r & 7)) * 8;
      ah[mf] = *(const bf16x8*)&ZL[o];
    }
#pragma unroll
    for (int nf = 0; nf < 2; ++nf) {
      int c = wid * 32 + nf * 16 + (lane & 15);
      size_t o = (size_t)c * 256 + ks * 32 + (lane >> 4) * 8;
      bh[nf] = *(const bf16x8*)&Bh[o];
      bl[nf] = *(const bf16x8*)&Bl[o];
    }
#pragma unroll
    for (int mf = 0; mf < 4; ++mf)
#pragma unroll
      for (int nf = 0; nf < 2; ++nf) {
        acc[mf][nf] = __builtin_amdgcn_mfma_f32_16x16x32_bf16(
            ah[mf], bh[nf], acc[mf][nf], 0, 0, 0);
        acc[mf][nf] = __builtin_amdgcn_mfma_f32_16x16x32_bf16(
            ah[mf], bl[nf], acc[mf][nf], 0, 0, 0);
      }
  }

#pragma unroll
  for (int mf = 0; mf < 4; ++mf) {
    int r0 = row0 + mf * 16 + (lane >> 4) * 4;
#pragma unroll
    for (int nf = 0; nf < 2; ++nf) {
      int c = wid * 32 + nf * 16 + (lane & 15);
#pragma unroll
      for (int r = 0; r < 4; ++r)
        if (r0 + r < M) Cbf[(size_t)(r0 + r) * F + c] = f2bf(acc[mf][nf][r]);
    }
  }
}

extern "C" void kernel_launch(void* const* d_in, const int* in_sizes, int n_in,
                              void* d_out, int out_size, void* d_ws, size_t ws_size,
                              hipStream_t stream) {
  const float* x = (const float*)d_in[0];
  const int* ei = (const int*)d_in[1];
  const float* W1 = (const float*)d_in[2];
  const float* b1 = (const float*)d_in[3];
  const float* W2 = (const float*)d_in[4];
  const float* b2 = (const float*)d_in[5];
  float* out = (float*)d_out;

  int N = in_sizes[0] / F;  // 50000
  int E = in_sizes[1] / 2;  // 800000
  const int* src = ei;
  const int* dst = ei + E;
  int P = (N + 255) / 256;  // dst buckets of 256 nodes (P <= 256 since N < 65536)

  // workspace layout (byte-based, 256B aligned chunks)
  char* ws = (char*)d_ws;
  size_t off = 0;
  auto allocB = [&](size_t bytes) {
    void* p = ws + off;
    off += ((bytes + 255) & ~(size_t)255);
    return p;
  };
  unsigned* deg = (unsigned*)allocB((size_t)N * 4);
  float* dinv = (float*)allocB((size_t)N * 4);
  int* rowptr = (int*)allocB(((size_t)N + 1) * 4);
  unsigned* bcnt = (unsigned*)allocB(256 * 4);
  unsigned* bbase = (unsigned*)allocB(257 * 4);
  unsigned* bcur = (unsigned*)allocB(256 * 4);
  unsigned* packed = (unsigned*)allocB((size_t)E * 4);
  int* esrc = (int*)allocB((size_t)E * 4);
  unsigned short* xb = (unsigned short*)allocB((size_t)N * F * 2);  // x bf16 table
  // +64 row padding so tail-block LDS staging reads stay in-bounds
  unsigned short* aggh = (unsigned short*)allocB((size_t)(N + 64) * F * 2);
  unsigned short* aggl = (unsigned short*)allocB((size_t)(N + 64) * F * 2);
  unsigned short* z1h = (unsigned short*)allocB((size_t)(N + 64) * HID * 2);
  unsigned short* w1th = (unsigned short*)allocB((size_t)F * HID * 2);
  unsigned short* w1tl = (unsigned short*)allocB((size_t)F * HID * 2);
  unsigned short* w2th = (unsigned short*)allocB((size_t)HID * F * 2);
  unsigned short* w2tl = (unsigned short*)allocB((size_t)HID * F * 2);
  // h2 bf16 (12.8MB) reuses the aggh plane (dead after GEMM1)
  unsigned short* h2b = aggh;

  int nbN = (N + 255) / 256;
  int nbW = (F * HID + 255) / 256;
  int nbX = (N * F / 4 + 255) / 256;
  int nbC = (E + ECHUNK - 1) / ECHUNK;

  k_wsplit<<<nbW, 256, 0, stream>>>(W1, w1th, w1tl, F, HID);  // [256][128]
  k_wsplit<<<nbW, 256, 0, stream>>>(W2, w2th, w2tl, HID, F);  // [128][256]
  k_tobf<<<nbX, 256, 0, stream>>>(x, xb, N * F / 4);

  // CSR build via bucketed counting sort
  k_bzero<<<1, 256, 0, stream>>>(bcnt);
  k_binc<<<nbC, 256, 0, stream>>>(dst, bcnt, E);
  k_bscan<<<1, 256, 0, stream>>>(bcnt, bbase, bcur, rowptr, P, N, E);
  k_binscat<<<nbC, 256, 0, stream>>>(src, dst, bcur, packed, E);
  k_bcsr<<<P, 256, 0, stream>>>(packed, bbase, deg, rowptr, esrc, N);
  k_dinv<<<nbN, 256, 0, stream>>>(deg, dinv, N);

  int nbAgg = (N + 3) / 4;
  int mb = (N + 63) / 64;

  // layer 1: agg(hi/lo) = A x  (bf16 gather) ; z1(bf16) = relu(agg @ W1 + b1)
  k_agg_bf<<<nbAgg, 256, 0, stream>>>(rowptr, esrc, dinv, x, xb, aggh, aggl, N);
  k_gemm1<<<mb, 256, 0, stream>>>(aggh, aggl, w1th, w1tl, b1, z1h, N);

  // layer 2: h2(bf16) = z1 @ W2 ; out = b2 + A h2  (bf16 gather)
  k_gemm2<<<mb, 256, 0, stream>>>(z1h, w2th, w2tl, h2b, N);
  k_agg_out<<<nbAgg, 256, 0, stream>>>(rowptr, esrc, dinv, h2b, b2, out, N);
}

// Round 10
// 173.315 us; speedup vs baseline: 1.3624x; 1.1275x over previous
//
#include <hip/hip_runtime.h>

// GCN decoder: z2 = A( relu(A(x)@W1 + b1) )@W2 + b2,  A = D^-1/2 (Adj+I) D^-1/2
// Aggregation at width-128 both layers, CSR via bucketed counting sort.
// Round 10: f16 end-to-end numerics (2^-11 rounding) with SINGLE-term f16 MFMA
// GEMMs (replaces bf16 3-term): 3x fewer MFMAs in GEMM1, 2x in GEMM2,
// half the LDS, lower VGPR pressure, col-tiled GEMM1 for occupancy.

constexpr int F = 128;    // aggregation width
constexpr int HID = 256;  // hidden width
constexpr int ECHUNK = 8192;  // edges per binning block

typedef __attribute__((ext_vector_type(8))) _Float16 f16x8;
typedef __attribute__((ext_vector_type(4))) _Float16 f16x4;
typedef __attribute__((ext_vector_type(2))) _Float16 f16x2;
typedef __attribute__((ext_vector_type(4))) float f32x4;

__global__ __launch_bounds__(256) void k_bzero(unsigned* bcnt) {
  bcnt[threadIdx.x] = 0u;
}

// binning pass 1: per-block LDS histogram of dst buckets -> global bucket counts
__global__ __launch_bounds__(256) void k_binc(const int* __restrict__ dst,
                                              unsigned* __restrict__ bcnt, int E) {
  __shared__ unsigned hist[256];
  int tid = threadIdx.x;
  hist[tid] = 0u;
  __syncthreads();
  int i0 = blockIdx.x * ECHUNK;
  int i1 = min(i0 + ECHUNK, E);
  for (int i = i0 + tid; i < i1; i += 256)
    atomicAdd(&hist[((unsigned)dst[i]) >> 8], 1u);
  __syncthreads();
  unsigned c = hist[tid];
  if (c) atomicAdd(&bcnt[tid], c);
}

// scan bucket counts -> bbase[P+1], init bcur, write rowptr[N]=E
__global__ __launch_bounds__(256) void k_bscan(const unsigned* __restrict__ bcnt,
                                               unsigned* __restrict__ bbase,
                                               unsigned* __restrict__ bcur,
                                               int* __restrict__ rowptr,
                                               int P, int N, int E) {
  __shared__ unsigned wsum[4];
  int tid = threadIdx.x;
  unsigned v = (tid < P) ? bcnt[tid] : 0u;
  unsigned sv = v;
#pragma unroll
  for (int off = 1; off < 64; off <<= 1) {
    unsigned t = __shfl_up(sv, off);
    if ((tid & 63) >= off) sv += t;
  }
  int w = tid >> 6;
  if ((tid & 63) == 63) wsum[w] = sv;
  __syncthreads();
  unsigned wpre = 0;
  for (int k = 0; k < w; ++k) wpre += wsum[k];
  unsigned excl = wpre + sv - v;
  if (tid < P) {
    bbase[tid] = excl;
    bcur[tid] = excl;
  }
  if (tid == P - 1) bbase[P] = excl + v;
  if (tid == 0) rowptr[N] = E;
}

// binning pass 2: reserve per-(block,bucket) ranges, write packed edges
// packed = src | (dst&255)<<16
__global__ __launch_bounds__(256) void k_binscat(const int* __restrict__ src,
                                                 const int* __restrict__ dst,
                                                 unsigned* __restrict__ bcur,
                                                 unsigned* __restrict__ packed, int E) {
  __shared__ unsigned hist[256];
  __shared__ unsigned basel[256];
  int tid = threadIdx.x;
  hist[tid] = 0u;
  __syncthreads();
  int i0 = blockIdx.x * ECHUNK;
  int i1 = min(i0 + ECHUNK, E);
  for (int i = i0 + tid; i < i1; i += 256)
    atomicAdd(&hist[((unsigned)dst[i]) >> 8], 1u);
  __syncthreads();
  unsigned c = hist[tid];
  if (c) basel[tid] = atomicAdd(&bcur[tid], c);
  __syncthreads();
  hist[tid] = 0u;  // reuse as local cursor
  __syncthreads();
  for (int i = i0 + tid; i < i1; i += 256) {
    unsigned d = (unsigned)dst[i];
    unsigned b = d >> 8;
    unsigned pos = basel[b] + atomicAdd(&hist[b], 1u);
    packed[pos] = ((unsigned)src[i]) | ((d & 255u) << 16);
  }
}

// per-bucket CSR finalize: deg, rowptr (coalesced), esrc (LDS-cursor scatter)
__global__ __launch_bounds__(256) void k_bcsr(const unsigned* __restrict__ packed,
                                              const unsigned* __restrict__ bbase,
                                              unsigned* __restrict__ deg,
                                              int* __restrict__ rowptr,
                                              int* __restrict__ esrc, int N) {
  __shared__ unsigned hist[256];
  __shared__ unsigned rowloc[256];
  __shared__ unsigned cur[256];
  __shared__ unsigned wsum[4];
  int tid = threadIdx.x, b = blockIdx.x;
  int e0 = (int)bbase[b], e1 = (int)bbase[b + 1];
  hist[tid] = 0u;
  __syncthreads();
  for (int i = e0 + tid; i < e1; i += 256)
    atomicAdd(&hist[packed[i] >> 16], 1u);
  __syncthreads();
  unsigned v = hist[tid];
  unsigned sv = v;
#pragma unroll
  for (int off = 1; off < 64; off <<= 1) {
    unsigned t = __shfl_up(sv, off);
    if ((tid & 63) >= off) sv += t;
  }
  int w = tid >> 6;
  if ((tid & 63) == 63) wsum[w] = sv;
  __syncthreads();
  unsigned wpre = 0;
  for (int k = 0; k < w; ++k) wpre += wsum[k];
  unsigned excl = wpre + sv - v;
  int node = b * 256 + tid;
  if (node < N) {
    deg[node] = v;
    rowptr[node] = e0 + (int)excl;
  }
  rowloc[tid] = (unsigned)e0 + excl;
  cur[tid] = 0u;
  __syncthreads();
  for (int i = e0 + tid; i < e1; i += 256) {
    unsigned pk = packed[i];
    unsigned dl = pk >> 16;
    unsigned pos = rowloc[dl] + atomicAdd(&cur[dl], 1u);
    esrc[pos] = (int)(pk & 0xffffu);
  }
}

__global__ __launch_bounds__(256) void k_dinv(const unsigned* __restrict__ deg,
                                              float* dinv, int N) {
  int i = blockIdx.x * 256 + threadIdx.x;
  if (i < N) dinv[i] = rsqrtf((float)deg[i] + 1.0f);  // +1 = self-loop
}

// fp32 -> f16 plane (x table for layer-1 gather)
__global__ __launch_bounds__(256) void k_toh(const float* __restrict__ in,
                                             _Float16* __restrict__ outp, int n4) {
  int i = blockIdx.x * 256 + threadIdx.x;
  if (i >= n4) return;
  float4 v = ((const float4*)in)[i];
  f16x4 o;
  o.x = (_Float16)v.x; o.y = (_Float16)v.y;
  o.z = (_Float16)v.z; o.w = (_Float16)v.w;
  ((f16x4*)outp)[i] = o;
}

// transpose W[K][Nn] -> f16 [Nn][K]
__global__ __launch_bounds__(256) void k_wcvt(const float* __restrict__ W,
                                              _Float16* __restrict__ Wt,
                                              int K, int Nn) {
  int idx = blockIdx.x * 256 + threadIdx.x;
  if (idx >= K * Nn) return;
  int k = idx / Nn, n = idx - k * Nn;
  Wt[n * K + k] = (_Float16)W[idx];
}

// Layer-1 agg: gather f16 x rows, w = dinv[s]*dinv[node] on the fly,
// self-term fp32, write f16 plane.
__global__ __launch_bounds__(256) void k_agg1(const int* __restrict__ rowptr,
                                              const int* __restrict__ esrc,
                                              const float* __restrict__ dinv,
                                              const float* __restrict__ xf,
                                              const _Float16* __restrict__ xh,
                                              _Float16* __restrict__ outp, int N) {
  int node = blockIdx.x * 4 + (threadIdx.x >> 6);
  int lane = threadIdx.x & 63;
  if (node >= N) return;
  float di = dinv[node];
  float w0 = di * di;
  float2 acc = ((const float2*)(xf + (size_t)node * F))[lane];
  acc.x *= w0; acc.y *= w0;
  int beg = rowptr[node], end = rowptr[node + 1];
  for (int b = beg; b < end; b += 64) {
    int n = min(64, end - b);
    int s = 0;
    float w = 0.f;
    if (lane < n) {
      s = esrc[b + lane];
      w = dinv[s] * di;
    }
    int t = 0;
    for (; t + 3 < n; t += 4) {
      int s0 = __shfl(s, t), s1 = __shfl(s, t + 1);
      int s2 = __shfl(s, t + 2), s3 = __shfl(s, t + 3);
      float wa = __shfl(w, t), wb = __shfl(w, t + 1);
      float wc = __shfl(w, t + 2), wd = __shfl(w, t + 3);
      f16x2 v0 = ((const f16x2*)(xh + (size_t)s0 * F))[lane];
      f16x2 v1 = ((const f16x2*)(xh + (size_t)s1 * F))[lane];
      f16x2 v2 = ((const f16x2*)(xh + (size_t)s2 * F))[lane];
      f16x2 v3 = ((const f16x2*)(xh + (size_t)s3 * F))[lane];
      acc.x += (float)v0.x * wa; acc.y += (float)v0.y * wa;
      acc.x += (float)v1.x * wb; acc.y += (float)v1.y * wb;
      acc.x += (float)v2.x * wc; acc.y += (float)v2.y * wc;
      acc.x += (float)v3.x * wd; acc.y += (float)v3.y * wd;
    }
    for (; t < n; ++t) {
      int s0 = __shfl(s, t);
      float wa = __shfl(w, t);
      f16x2 v0 = ((const f16x2*)(xh + (size_t)s0 * F))[lane];
      acc.x += (float)v0.x * wa; acc.y += (float)v0.y * wa;
    }
  }
  f16x2 ov;
  ov.x = (_Float16)acc.x;
  ov.y = (_Float16)acc.y;
  ((f16x2*)(outp + (size_t)node * F))[lane] = ov;
}

// Layer-2 agg: gather f16 h2 rows, w on the fly, + bias -> fp32 out (final)
__global__ __launch_bounds__(256) void k_agg_out(const int* __restrict__ rowptr,
                                                 const int* __restrict__ esrc,
                                                 const float* __restrict__ dinv,
                                                 const _Float16* __restrict__ hb,
                                                 const float* __restrict__ bias,
                                                 float* __restrict__ outp, int N) {
  int node = blockIdx.x * 4 + (threadIdx.x >> 6);
  int lane = threadIdx.x & 63;
  if (node >= N) return;
  float di = dinv[node];
  float w0 = di * di;
  f16x2 sv2 = ((const f16x2*)(hb + (size_t)node * F))[lane];
  float2 bb = ((const float2*)bias)[lane];
  float2 acc;
  acc.x = (float)sv2.x * w0 + bb.x;
  acc.y = (float)sv2.y * w0 + bb.y;
  int beg = rowptr[node], end = rowptr[node + 1];
  for (int b = beg; b < end; b += 64) {
    int n = min(64, end - b);
    int s = 0;
    float w = 0.f;
    if (lane < n) {
      s = esrc[b + lane];
      w = dinv[s] * di;
    }
    int t = 0;
    for (; t + 3 < n; t += 4) {
      int s0 = __shfl(s, t), s1 = __shfl(s, t + 1);
      int s2 = __shfl(s, t + 2), s3 = __shfl(s, t + 3);
      float wa = __shfl(w, t), wb = __shfl(w, t + 1);
      float wc = __shfl(w, t + 2), wd = __shfl(w, t + 3);
      f16x2 v0 = ((const f16x2*)(hb + (size_t)s0 * F))[lane];
      f16x2 v1 = ((const f16x2*)(hb + (size_t)s1 * F))[lane];
      f16x2 v2 = ((const f16x2*)(hb + (size_t)s2 * F))[lane];
      f16x2 v3 = ((const f16x2*)(hb + (size_t)s3 * F))[lane];
      acc.x += (float)v0.x * wa; acc.y += (float)v0.y * wa;
      acc.x += (float)v1.x * wb; acc.y += (float)v1.y * wb;
      acc.x += (float)v2.x * wc; acc.y += (float)v2.y * wc;
      acc.x += (float)v3.x * wd; acc.y += (float)v3.y * wd;
    }
    for (; t < n; ++t) {
      int s0 = __shfl(s, t);
      float wa = __shfl(w, t);
      f16x2 v0 = ((const f16x2*)(hb + (size_t)s0 * F))[lane];
      acc.x += (float)v0.x * wa; acc.y += (float)v0.y * wa;
    }
  }
  ((float2*)(outp + (size_t)node * F))[lane] = acc;
}

// GEMM1: z1(f16) = relu( A(f16)[M,128] @ W1t(f16)[256,128]^T + b1 )
// grid (mb, 2): block = 64 rows x 128 cols; 4 waves x 32 cols; acc[4][2].
// Whole K=128 of A in LDS (16 KB, XOR-swizzled), single barrier; B from global (L2-hot).
__global__ __launch_bounds__(256) void k_gemm1(const _Float16* __restrict__ A,
                                               const _Float16* __restrict__ Bt,
                                               const float* __restrict__ bias,
                                               _Float16* __restrict__ C, int M) {
  __shared__ _Float16 AL[64 * 128];
  int tid = threadIdx.x;
  int lane = tid & 63, wid = tid >> 6;
  int row0 = blockIdx.x * 64;
  int col0 = blockIdx.y * 128;

  // stage A: 1024 granules (16B), 4 per thread, swizzled ds_write
#pragma unroll
  for (int i = 0; i < 4; ++i) {
    int g = i * 256 + tid;
    int r = g >> 4, gi = g & 15;
    int o = r * 128 + ((gi ^ (r & 7)) * 8);
    size_t go = (size_t)(row0 + r) * 128 + gi * 8;
    *(f16x8*)&AL[o] = *(const f16x8*)&A[go];
  }
  __syncthreads();

  f32x4 acc[4][2] = {};
#pragma unroll
  for (int ks = 0; ks < 4; ++ks) {
    f16x8 ah[4], bh[2];
#pragma unroll
    for (int mf = 0; mf < 4; ++mf) {
      int r = mf * 16 + (lane & 15);
      int g = ks * 4 + (lane >> 4);
      int o = r * 128 + ((g ^ (r & 7)) * 8);
      ah[mf] = *(const f16x8*)&AL[o];
    }
#pragma unroll
    for (int nf = 0; nf < 2; ++nf) {
      int c = col0 + wid * 32 + nf * 16 + (lane & 15);
      size_t o = (size_t)c * 128 + ks * 32 + (lane >> 4) * 8;
      bh[nf] = *(const f16x8*)&Bt[o];
    }
#pragma unroll
    for (int mf = 0; mf < 4; ++mf)
#pragma unroll
      for (int nf = 0; nf < 2; ++nf)
        acc[mf][nf] = __builtin_amdgcn_mfma_f32_16x16x32_f16(
            ah[mf], bh[nf], acc[mf][nf], 0, 0, 0);
  }

  // epilogue: D col=lane&15, row=(lane>>4)*4+reg
#pragma unroll
  for (int mf = 0; mf < 4; ++mf) {
    int r0 = row0 + mf * 16 + (lane >> 4) * 4;
#pragma unroll
    for (int nf = 0; nf < 2; ++nf) {
      int c = col0 + wid * 32 + nf * 16 + (lane & 15);
      float bv = bias[c];
#pragma unroll
      for (int r = 0; r < 4; ++r) {
        if (r0 + r < M) {
          float v = fmaxf(acc[mf][nf][r] + bv, 0.f);
          C[(size_t)(r0 + r) * HID + c] = (_Float16)v;
        }
      }
    }
  }
}

// GEMM2: h2(f16) = Z(f16)[M,256] @ W2t(f16)[128,256]^T
// block = 64 rows x 128 cols; 4 waves x 32 cols; whole K=256 of Z in LDS (32 KB).
__global__ __launch_bounds__(256) void k_gemm2(const _Float16* __restrict__ Z,
                                               const _Float16* __restrict__ Bt,
                                               _Float16* __restrict__ C, int M) {
  __shared__ _Float16 ZL[64 * 256];
  int tid = threadIdx.x;
  int lane = tid & 63, wid = tid >> 6;
  int row0 = blockIdx.x * 64;

  // stage Z: 2048 granules, 8 per thread, swizzled
#pragma unroll
  for (int i = 0; i < 8; ++i) {
    int g = i * 256 + tid;
    int r = g >> 5, gi = g & 31;
    int o = r * 256 + ((gi ^ (r & 7)) * 8);
    size_t go = (size_t)(row0 + r) * 256 + gi * 8;
    *(f16x8*)&ZL[o] = *(const f16x8*)&Z[go];
  }
  __syncthreads();

  f32x4 acc[4][2] = {};
#pragma unroll
  for (int ks = 0; ks < 8; ++ks) {
    f16x8 ah[4], bh[2];
#pragma unroll
    for (int mf = 0; mf < 4; ++mf) {
      int r = mf * 16 + (lane & 15);
      int g = ks * 4 + (lane >> 4);
      int o = r * 256 + ((g ^ (r & 7)) * 8);
      ah[mf] = *(const f16x8*)&ZL[o];
    }
#pragma unroll
    for (int nf = 0; nf < 2; ++nf) {
      int c = wid * 32 + nf * 16 + (lane & 15);
      size_t o = (size_t)c * 256 + ks * 32 + (lane >> 4) * 8;
      bh[nf] = *(const f16x8*)&Bt[o];
    }
#pragma unroll
    for (int mf = 0; mf < 4; ++mf)
#pragma unroll
      for (int nf = 0; nf < 2; ++nf)
        acc[mf][nf] = __builtin_amdgcn_mfma_f32_16x16x32_f16(
            ah[mf], bh[nf], acc[mf][nf], 0, 0, 0);
  }

#pragma unroll
  for (int mf = 0; mf < 4; ++mf) {
    int r0 = row0 + mf * 16 + (lane >> 4) * 4;
#pragma unroll
    for (int nf = 0; nf < 2; ++nf) {
      int c = wid * 32 + nf * 16 + (lane & 15);
#pragma unroll
      for (int r = 0; r < 4; ++r)
        if (r0 + r < M) C[(size_t)(r0 + r) * F + c] = (_Float16)acc[mf][nf][r];
    }
  }
}

extern "C" void kernel_launch(void* const* d_in, const int* in_sizes, int n_in,
                              void* d_out, int out_size, void* d_ws, size_t ws_size,
                              hipStream_t stream) {
  const float* x = (const float*)d_in[0];
  const int* ei = (const int*)d_in[1];
  const float* W1 = (const float*)d_in[2];
  const float* b1 = (const float*)d_in[3];
  const float* W2 = (const float*)d_in[4];
  const float* b2 = (const float*)d_in[5];
  float* out = (float*)d_out;

  int N = in_sizes[0] / F;  // 50000
  int E = in_sizes[1] / 2;  // 800000
  const int* src = ei;
  const int* dst = ei + E;
  int P = (N + 255) / 256;  // dst buckets of 256 nodes (N < 65536)

  // workspace layout (byte-based, 256B aligned chunks)
  char* ws = (char*)d_ws;
  size_t off = 0;
  auto allocB = [&](size_t bytes) {
    void* p = ws + off;
    off += ((bytes + 255) & ~(size_t)255);
    return p;
  };
  unsigned* deg = (unsigned*)allocB((size_t)N * 4);
  float* dinv = (float*)allocB((size_t)N * 4);
  int* rowptr = (int*)allocB(((size_t)N + 1) * 4);
  unsigned* bcnt = (unsigned*)allocB(256 * 4);
  unsigned* bbase = (unsigned*)allocB(257 * 4);
  unsigned* bcur = (unsigned*)allocB(256 * 4);
  unsigned* packed = (unsigned*)allocB((size_t)E * 4);
  int* esrc = (int*)allocB((size_t)E * 4);
  _Float16* xh = (_Float16*)allocB((size_t)N * F * 2);  // x f16 table
  // +64 row padding so tail-block LDS staging reads stay in-bounds
  _Float16* agg = (_Float16*)allocB((size_t)(N + 64) * F * 2);
  _Float16* z1 = (_Float16*)allocB((size_t)(N + 64) * HID * 2);
  _Float16* w1t = (_Float16*)allocB((size_t)F * HID * 2);
  _Float16* w2t = (_Float16*)allocB((size_t)HID * F * 2);
  // h2 f16 (12.8MB) reuses the agg plane (dead after GEMM1)
  _Float16* h2 = agg;

  int nbN = (N + 255) / 256;
  int nbW = (F * HID + 255) / 256;
  int nbX = (N * F / 4 + 255) / 256;
  int nbC = (E + ECHUNK - 1) / ECHUNK;

  k_wcvt<<<nbW, 256, 0, stream>>>(W1, w1t, F, HID);  // [256][128]
  k_wcvt<<<nbW, 256, 0, stream>>>(W2, w2t, HID, F);  // [128][256]
  k_toh<<<nbX, 256, 0, stream>>>(x, xh, N * F / 4);

  // CSR build via bucketed counting sort
  k_bzero<<<1, 256, 0, stream>>>(bcnt);
  k_binc<<<nbC, 256, 0, stream>>>(dst, bcnt, E);
  k_bscan<<<1, 256, 0, stream>>>(bcnt, bbase, bcur, rowptr, P, N, E);
  k_binscat<<<nbC, 256, 0, stream>>>(src, dst, bcur, packed, E);
  k_bcsr<<<P, 256, 0, stream>>>(packed, bbase, deg, rowptr, esrc, N);
  k_dinv<<<nbN, 256, 0, stream>>>(deg, dinv, N);

  int nbAgg = (N + 3) / 4;
  int mb = (N + 63) / 64;

  // layer 1: agg(f16) = A x  (f16 gather) ; z1(f16) = relu(agg @ W1 + b1)
  k_agg1<<<nbAgg, 256, 0, stream>>>(rowptr, esrc, dinv, x, xh, agg, N);
  dim3 g1(mb, 2);
  k_gemm1<<<g1, 256, 0, stream>>>(agg, w1t, b1, z1, N);

  // layer 2: h2(f16) = z1 @ W2 ; out = b2 + A h2  (f16 gather)
  k_gemm2<<<mb, 256, 0, stream>>>(z1, w2t, h2, N);
  k_agg_out<<<nbAgg, 256, 0, stream>>>(rowptr, esrc, dinv, h2, b2, out, N);
}

// Round 11
// 170.436 us; speedup vs baseline: 1.3854x; 1.0169x over previous
//
#include <hip/hip_runtime.h>

// GCN decoder: z2 = A( relu(A(x)@W1 + b1) )@W2 + b2,  A = D^-1/2 (Adj+I) D^-1/2
// f16 numerics end-to-end, CSR via bucketed counting sort, width-128 aggregation.
// Round 11: single-pass GEMM1 (64x256, A staged once); binscat reuses binc's
// per-block histograms; dinv fused into bcsr; agg gather unrolled 8-deep.

constexpr int F = 128;    // aggregation width
constexpr int HID = 256;  // hidden width
constexpr int ECHUNK = 8192;  // edges per binning block

typedef __attribute__((ext_vector_type(8))) _Float16 f16x8;
typedef __attribute__((ext_vector_type(4))) _Float16 f16x4;
typedef __attribute__((ext_vector_type(2))) _Float16 f16x2;
typedef __attribute__((ext_vector_type(4))) float f32x4;

__global__ __launch_bounds__(256) void k_bzero(unsigned* bcnt) {
  bcnt[threadIdx.x] = 0u;
}

// binning pass 1: per-block LDS histogram of dst buckets;
// saves per-block hist (for binscat) + global bucket counts
__global__ __launch_bounds__(256) void k_binc(const int* __restrict__ dst,
                                              unsigned* __restrict__ bcnt,
                                              unsigned* __restrict__ bhist, int E) {
  __shared__ unsigned hist[256];
  int tid = threadIdx.x;
  hist[tid] = 0u;
  __syncthreads();
  int i0 = blockIdx.x * ECHUNK;
  int i1 = min(i0 + ECHUNK, E);
  for (int i = i0 + tid; i < i1; i += 256)
    atomicAdd(&hist[((unsigned)dst[i]) >> 8], 1u);
  __syncthreads();
  unsigned c = hist[tid];
  bhist[blockIdx.x * 256 + tid] = c;
  if (c) atomicAdd(&bcnt[tid], c);
}

// scan bucket counts -> bbase[P+1], init bcur, write rowptr[N]=E
__global__ __launch_bounds__(256) void k_bscan(const unsigned* __restrict__ bcnt,
                                               unsigned* __restrict__ bbase,
                                               unsigned* __restrict__ bcur,
                                               int* __restrict__ rowptr,
                                               int P, int N, int E) {
  __shared__ unsigned wsum[4];
  int tid = threadIdx.x;
  unsigned v = (tid < P) ? bcnt[tid] : 0u;
  unsigned sv = v;
#pragma unroll
  for (int off = 1; off < 64; off <<= 1) {
    unsigned t = __shfl_up(sv, off);
    if ((tid & 63) >= off) sv += t;
  }
  int w = tid >> 6;
  if ((tid & 63) == 63) wsum[w] = sv;
  __syncthreads();
  unsigned wpre = 0;
  for (int k = 0; k < w; ++k) wpre += wsum[k];
  unsigned excl = wpre + sv - v;
  if (tid < P) {
    bbase[tid] = excl;
    bcur[tid] = excl;
  }
  if (tid == P - 1) bbase[P] = excl + v;
  if (tid == 0) rowptr[N] = E;
}

// binning pass 2: reserve ranges using precomputed per-block hist, write packed
// packed = src | (dst&255)<<16
__global__ __launch_bounds__(256) void k_binscat(const int* __restrict__ src,
                                                 const int* __restrict__ dst,
                                                 const unsigned* __restrict__ bhist,
                                                 unsigned* __restrict__ bcur,
                                                 unsigned* __restrict__ packed, int E) {
  __shared__ unsigned hist[256];
  __shared__ unsigned basel[256];
  int tid = threadIdx.x;
  unsigned c = bhist[blockIdx.x * 256 + tid];
  if (c) basel[tid] = atomicAdd(&bcur[tid], c);
  hist[tid] = 0u;
  __syncthreads();
  int i0 = blockIdx.x * ECHUNK;
  int i1 = min(i0 + ECHUNK, E);
  for (int i = i0 + tid; i < i1; i += 256) {
    unsigned d = (unsigned)dst[i];
    unsigned b = d >> 8;
    unsigned pos = basel[b] + atomicAdd(&hist[b], 1u);
    packed[pos] = ((unsigned)src[i]) | ((d & 255u) << 16);
  }
}

// per-bucket CSR finalize: dinv + rowptr (coalesced), esrc (LDS-cursor scatter)
__global__ __launch_bounds__(256) void k_bcsr(const unsigned* __restrict__ packed,
                                              const unsigned* __restrict__ bbase,
                                              float* __restrict__ dinv,
                                              int* __restrict__ rowptr,
                                              int* __restrict__ esrc, int N) {
  __shared__ unsigned hist[256];
  __shared__ unsigned rowloc[256];
  __shared__ unsigned cur[256];
  __shared__ unsigned wsum[4];
  int tid = threadIdx.x, b = blockIdx.x;
  int e0 = (int)bbase[b], e1 = (int)bbase[b + 1];
  hist[tid] = 0u;
  __syncthreads();
  for (int i = e0 + tid; i < e1; i += 256)
    atomicAdd(&hist[packed[i] >> 16], 1u);
  __syncthreads();
  unsigned v = hist[tid];
  unsigned sv = v;
#pragma unroll
  for (int off = 1; off < 64; off <<= 1) {
    unsigned t = __shfl_up(sv, off);
    if ((tid & 63) >= off) sv += t;
  }
  int w = tid >> 6;
  if ((tid & 63) == 63) wsum[w] = sv;
  __syncthreads();
  unsigned wpre = 0;
  for (int k = 0; k < w; ++k) wpre += wsum[k];
  unsigned excl = wpre + sv - v;
  int node = b * 256 + tid;
  if (node < N) {
    dinv[node] = rsqrtf((float)v + 1.0f);  // +1 = self-loop
    rowptr[node] = e0 + (int)excl;
  }
  rowloc[tid] = (unsigned)e0 + excl;
  cur[tid] = 0u;
  __syncthreads();
  for (int i = e0 + tid; i < e1; i += 256) {
    unsigned pk = packed[i];
    unsigned dl = pk >> 16;
    unsigned pos = rowloc[dl] + atomicAdd(&cur[dl], 1u);
    esrc[pos] = (int)(pk & 0xffffu);
  }
}

// fp32 -> f16 plane (x table for layer-1 gather)
__global__ __launch_bounds__(256) void k_toh(const float* __restrict__ in,
                                             _Float16* __restrict__ outp, int n4) {
  int i = blockIdx.x * 256 + threadIdx.x;
  if (i >= n4) return;
  float4 v = ((const float4*)in)[i];
  f16x4 o;
  o.x = (_Float16)v.x; o.y = (_Float16)v.y;
  o.z = (_Float16)v.z; o.w = (_Float16)v.w;
  ((f16x4*)outp)[i] = o;
}

// transpose W[K][Nn] -> f16 [Nn][K]
__global__ __launch_bounds__(256) void k_wcvt(const float* __restrict__ W,
                                              _Float16* __restrict__ Wt,
                                              int K, int Nn) {
  int idx = blockIdx.x * 256 + threadIdx.x;
  if (idx >= K * Nn) return;
  int k = idx / Nn, n = idx - k * Nn;
  Wt[n * K + k] = (_Float16)W[idx];
}

// Layer-1 agg: gather f16 x rows, w = dinv[s]*dinv[node] on the fly,
// self-term fp32, 8-deep unroll, write f16 plane.
__global__ __launch_bounds__(256) void k_agg1(const int* __restrict__ rowptr,
                                              const int* __restrict__ esrc,
                                              const float* __restrict__ dinv,
                                              const float* __restrict__ xf,
                                              const _Float16* __restrict__ xh,
                                              _Float16* __restrict__ outp, int N) {
  int node = blockIdx.x * 4 + (threadIdx.x >> 6);
  int lane = threadIdx.x & 63;
  if (node >= N) return;
  float di = dinv[node];
  float w0 = di * di;
  float2 acc = ((const float2*)(xf + (size_t)node * F))[lane];
  acc.x *= w0; acc.y *= w0;
  int beg = rowptr[node], end = rowptr[node + 1];
  for (int b = beg; b < end; b += 64) {
    int n = min(64, end - b);
    int s = 0;
    float w = 0.f;
    if (lane < n) {
      s = esrc[b + lane];
      w = dinv[s] * di;
    }
    int t = 0;
    for (; t + 7 < n; t += 8) {
      int ss[8];
      float wz[8];
#pragma unroll
      for (int j = 0; j < 8; ++j) {
        ss[j] = __shfl(s, t + j);
        wz[j] = __shfl(w, t + j);
      }
      f16x2 vv[8];
#pragma unroll
      for (int j = 0; j < 8; ++j)
        vv[j] = ((const f16x2*)(xh + (size_t)ss[j] * F))[lane];
#pragma unroll
      for (int j = 0; j < 8; ++j) {
        acc.x += (float)vv[j].x * wz[j];
        acc.y += (float)vv[j].y * wz[j];
      }
    }
    for (; t < n; ++t) {
      int s0 = __shfl(s, t);
      float wa = __shfl(w, t);
      f16x2 v0 = ((const f16x2*)(xh + (size_t)s0 * F))[lane];
      acc.x += (float)v0.x * wa;
      acc.y += (float)v0.y * wa;
    }
  }
  f16x2 ov;
  ov.x = (_Float16)acc.x;
  ov.y = (_Float16)acc.y;
  ((f16x2*)(outp + (size_t)node * F))[lane] = ov;
}

// Layer-2 agg: gather f16 h2 rows, w on the fly, + bias -> fp32 out (final)
__global__ __launch_bounds__(256) void k_agg_out(const int* __restrict__ rowptr,
                                                 const int* __restrict__ esrc,
                                                 const float* __restrict__ dinv,
                                                 const _Float16* __restrict__ hb,
                                                 const float* __restrict__ bias,
                                                 float* __restrict__ outp, int N) {
  int node = blockIdx.x * 4 + (threadIdx.x >> 6);
  int lane = threadIdx.x & 63;
  if (node >= N) return;
  float di = dinv[node];
  float w0 = di * di;
  f16x2 sv2 = ((const f16x2*)(hb + (size_t)node * F))[lane];
  float2 bb = ((const float2*)bias)[lane];
  float2 acc;
  acc.x = (float)sv2.x * w0 + bb.x;
  acc.y = (float)sv2.y * w0 + bb.y;
  int beg = rowptr[node], end = rowptr[node + 1];
  for (int b = beg; b < end; b += 64) {
    int n = min(64, end - b);
    int s = 0;
    float w = 0.f;
    if (lane < n) {
      s = esrc[b + lane];
      w = dinv[s] * di;
    }
    int t = 0;
    for (; t + 7 < n; t += 8) {
      int ss[8];
      float wz[8];
#pragma unroll
      for (int j = 0; j < 8; ++j) {
        ss[j] = __shfl(s, t + j);
        wz[j] = __shfl(w, t + j);
      }
      f16x2 vv[8];
#pragma unroll
      for (int j = 0; j < 8; ++j)
        vv[j] = ((const f16x2*)(hb + (size_t)ss[j] * F))[lane];
#pragma unroll
      for (int j = 0; j < 8; ++j) {
        acc.x += (float)vv[j].x * wz[j];
        acc.y += (float)vv[j].y * wz[j];
      }
    }
    for (; t < n; ++t) {
      int s0 = __shfl(s, t);
      float wa = __shfl(w, t);
      f16x2 v0 = ((const f16x2*)(hb + (size_t)s0 * F))[lane];
      acc.x += (float)v0.x * wa;
      acc.y += (float)v0.y * wa;
    }
  }
  ((float2*)(outp + (size_t)node * F))[lane] = acc;
}

// GEMM1: z1(f16) = relu( A(f16)[M,128] @ W1t(f16)[256,128]^T + b1 )
// block = 64 rows x 256 cols; 4 waves x 64 cols; acc[4][4]; A staged once (16 KB).
__global__ __launch_bounds__(256) void k_gemm1(const _Float16* __restrict__ A,
                                               const _Float16* __restrict__ Bt,
                                               const float* __restrict__ bias,
                                               _Float16* __restrict__ C, int M) {
  __shared__ _Float16 AL[64 * 128];
  int tid = threadIdx.x;
  int lane = tid & 63, wid = tid >> 6;
  int row0 = blockIdx.x * 64;

#pragma unroll
  for (int i = 0; i < 4; ++i) {
    int g = i * 256 + tid;
    int r = g >> 4, gi = g & 15;
    int o = r * 128 + ((gi ^ (r & 7)) * 8);
    size_t go = (size_t)(row0 + r) * 128 + gi * 8;
    *(f16x8*)&AL[o] = *(const f16x8*)&A[go];
  }
  __syncthreads();

  f32x4 acc[4][4] = {};
#pragma unroll
  for (int ks = 0; ks < 4; ++ks) {
    f16x8 ah[4], bh[4];
#pragma unroll
    for (int mf = 0; mf < 4; ++mf) {
      int r = mf * 16 + (lane & 15);
      int g = ks * 4 + (lane >> 4);
      int o = r * 128 + ((g ^ (r & 7)) * 8);
      ah[mf] = *(const f16x8*)&AL[o];
    }
#pragma unroll
    for (int nf = 0; nf < 4; ++nf) {
      int c = wid * 64 + nf * 16 + (lane & 15);
      size_t o = (size_t)c * 128 + ks * 32 + (lane >> 4) * 8;
      bh[nf] = *(const f16x8*)&Bt[o];
    }
#pragma unroll
    for (int mf = 0; mf < 4; ++mf)
#pragma unroll
      for (int nf = 0; nf < 4; ++nf)
        acc[mf][nf] = __builtin_amdgcn_mfma_f32_16x16x32_f16(
            ah[mf], bh[nf], acc[mf][nf], 0, 0, 0);
  }

  // epilogue: D col=lane&15, row=(lane>>4)*4+reg
#pragma unroll
  for (int mf = 0; mf < 4; ++mf) {
    int r0 = row0 + mf * 16 + (lane >> 4) * 4;
#pragma unroll
    for (int nf = 0; nf < 4; ++nf) {
      int c = wid * 64 + nf * 16 + (lane & 15);
      float bv = bias[c];
#pragma unroll
      for (int r = 0; r < 4; ++r) {
        if (r0 + r < M) {
          float v = fmaxf(acc[mf][nf][r] + bv, 0.f);
          C[(size_t)(r0 + r) * HID + c] = (_Float16)v;
        }
      }
    }
  }
}

// GEMM2: h2(f16) = Z(f16)[M,256] @ W2t(f16)[128,256]^T
// block = 64 rows x 128 cols; 4 waves x 32 cols; whole K=256 of Z in LDS (32 KB).
__global__ __launch_bounds__(256) void k_gemm2(const _Float16* __restrict__ Z,
                                               const _Float16* __restrict__ Bt,
                                               _Float16* __restrict__ C, int M) {
  __shared__ _Float16 ZL[64 * 256];
  int tid = threadIdx.x;
  int lane = tid & 63, wid = tid >> 6;
  int row0 = blockIdx.x * 64;

#pragma unroll
  for (int i = 0; i < 8; ++i) {
    int g = i * 256 + tid;
    int r = g >> 5, gi = g & 31;
    int o = r * 256 + ((gi ^ (r & 7)) * 8);
    size_t go = (size_t)(row0 + r) * 256 + gi * 8;
    *(f16x8*)&ZL[o] = *(const f16x8*)&Z[go];
  }
  __syncthreads();

  f32x4 acc[4][2] = {};
#pragma unroll
  for (int ks = 0; ks < 8; ++ks) {
    f16x8 ah[4], bh[2];
#pragma unroll
    for (int mf = 0; mf < 4; ++mf) {
      int r = mf * 16 + (lane & 15);
      int g = ks * 4 + (lane >> 4);
      int o = r * 256 + ((g ^ (r & 7)) * 8);
      ah[mf] = *(const f16x8*)&ZL[o];
    }
#pragma unroll
    for (int nf = 0; nf < 2; ++nf) {
      int c = wid * 32 + nf * 16 + (lane & 15);
      size_t o = (size_t)c * 256 + ks * 32 + (lane >> 4) * 8;
      bh[nf] = *(const f16x8*)&Bt[o];
    }
#pragma unroll
    for (int mf = 0; mf < 4; ++mf)
#pragma unroll
      for (int nf = 0; nf < 2; ++nf)
        acc[mf][nf] = __builtin_amdgcn_mfma_f32_16x16x32_f16(
            ah[mf], bh[nf], acc[mf][nf], 0, 0, 0);
  }

#pragma unroll
  for (int mf = 0; mf < 4; ++mf) {
    int r0 = row0 + mf * 16 + (lane >> 4) * 4;
#pragma unroll
    for (int nf = 0; nf < 2; ++nf) {
      int c = wid * 32 + nf * 16 + (lane & 15);
#pragma unroll
      for (int r = 0; r < 4; ++r)
        if (r0 + r < M) C[(size_t)(r0 + r) * F + c] = (_Float16)acc[mf][nf][r];
    }
  }
}

extern "C" void kernel_launch(void* const* d_in, const int* in_sizes, int n_in,
                              void* d_out, int out_size, void* d_ws, size_t ws_size,
                              hipStream_t stream) {
  const float* x = (const float*)d_in[0];
  const int* ei = (const int*)d_in[1];
  const float* W1 = (const float*)d_in[2];
  const float* b1 = (const float*)d_in[3];
  const float* W2 = (const float*)d_in[4];
  const float* b2 = (const float*)d_in[5];
  float* out = (float*)d_out;

  int N = in_sizes[0] / F;  // 50000
  int E = in_sizes[1] / 2;  // 800000
  const int* src = ei;
  const int* dst = ei + E;
  int P = (N + 255) / 256;  // dst buckets of 256 nodes (N < 65536)
  int nbC = (E + ECHUNK - 1) / ECHUNK;

  // workspace layout (byte-based, 256B aligned chunks)
  char* ws = (char*)d_ws;
  size_t off = 0;
  auto allocB = [&](size_t bytes) {
    void* p = ws + off;
    off += ((bytes + 255) & ~(size_t)255);
    return p;
  };
  float* dinv = (float*)allocB((size_t)N * 4);
  int* rowptr = (int*)allocB(((size_t)N + 1) * 4);
  unsigned* bcnt = (unsigned*)allocB(256 * 4);
  unsigned* bbase = (unsigned*)allocB(257 * 4);
  unsigned* bcur = (unsigned*)allocB(256 * 4);
  unsigned* bhist = (unsigned*)allocB((size_t)nbC * 256 * 4);
  unsigned* packed = (unsigned*)allocB((size_t)E * 4);
  int* esrc = (int*)allocB((size_t)E * 4);
  _Float16* xh = (_Float16*)allocB((size_t)N * F * 2);  // x f16 table
  // +64 row padding so tail-block LDS staging reads stay in-bounds
  _Float16* agg = (_Float16*)allocB((size_t)(N + 64) * F * 2);
  _Float16* z1 = (_Float16*)allocB((size_t)(N + 64) * HID * 2);
  _Float16* w1t = (_Float16*)allocB((size_t)F * HID * 2);
  _Float16* w2t = (_Float16*)allocB((size_t)HID * F * 2);
  // h2 f16 (12.8MB) reuses the agg plane (dead after GEMM1)
  _Float16* h2 = agg;

  int nbW = (F * HID + 255) / 256;
  int nbX = (N * F / 4 + 255) / 256;

  k_wcvt<<<nbW, 256, 0, stream>>>(W1, w1t, F, HID);  // [256][128]
  k_wcvt<<<nbW, 256, 0, stream>>>(W2, w2t, HID, F);  // [128][256]
  k_toh<<<nbX, 256, 0, stream>>>(x, xh, N * F / 4);

  // CSR build via bucketed counting sort
  k_bzero<<<1, 256, 0, stream>>>(bcnt);
  k_binc<<<nbC, 256, 0, stream>>>(dst, bcnt, bhist, E);
  k_bscan<<<1, 256, 0, stream>>>(bcnt, bbase, bcur, rowptr, P, N, E);
  k_binscat<<<nbC, 256, 0, stream>>>(src, dst, bhist, bcur, packed, E);
  k_bcsr<<<P, 256, 0, stream>>>(packed, bbase, dinv, rowptr, esrc, N);

  int nbAgg = (N + 3) / 4;
  int mb = (N + 63) / 64;

  // layer 1: agg(f16) = A x  (f16 gather) ; z1(f16) = relu(agg @ W1 + b1)
  k_agg1<<<nbAgg, 256, 0, stream>>>(rowptr, esrc, dinv, x, xh, agg, N);
  k_gemm1<<<mb, 256, 0, stream>>>(agg, w1t, b1, z1, N);

  // layer 2: h2(f16) = z1 @ W2 ; out = b2 + A h2  (f16 gather)
  k_gemm2<<<mb, 256, 0, stream>>>(z1, w2t, h2, N);
  k_agg_out<<<nbAgg, 256, 0, stream>>>(rowptr, esrc, dinv, h2, b2, out, N);
}

// Round 12
// 168.364 us; speedup vs baseline: 1.4025x; 1.0123x over previous
//
#include <hip/hip_runtime.h>

// GCN decoder: z2 = A( relu(A(x)@W1 + b1) )@W2 + b2,  A = D^-1/2 (Adj+I) D^-1/2
// f16 numerics end-to-end, CSR via bucketed counting sort, width-128 aggregation.
// Round 12: dual-row gather (lanes 0-31 row j, lanes 32-63 row j+1, f16x4/lane,
// shfl_xor(32) combine) -> 2x memory-level parallelism in the L3-bound aggs;
// self-term from f16 table; fused conversion kernel; memset for bcnt.

constexpr int F = 128;    // aggregation width
constexpr int HID = 256;  // hidden width
constexpr int ECHUNK = 8192;  // edges per binning block

typedef __attribute__((ext_vector_type(8))) _Float16 f16x8;
typedef __attribute__((ext_vector_type(4))) _Float16 f16x4;
typedef __attribute__((ext_vector_type(4))) float f32x4;

// binning pass 1: per-block LDS histogram of dst buckets;
// saves per-block hist (for binscat) + global bucket counts
__global__ __launch_bounds__(256) void k_binc(const int* __restrict__ dst,
                                              unsigned* __restrict__ bcnt,
                                              unsigned* __restrict__ bhist, int E) {
  __shared__ unsigned hist[256];
  int tid = threadIdx.x;
  hist[tid] = 0u;
  __syncthreads();
  int i0 = blockIdx.x * ECHUNK;
  int i1 = min(i0 + ECHUNK, E);
  for (int i = i0 + tid; i < i1; i += 256)
    atomicAdd(&hist[((unsigned)dst[i]) >> 8], 1u);
  __syncthreads();
  unsigned c = hist[tid];
  bhist[blockIdx.x * 256 + tid] = c;
  if (c) atomicAdd(&bcnt[tid], c);
}

// scan bucket counts -> bbase[P+1], init bcur, write rowptr[N]=E
__global__ __launch_bounds__(256) void k_bscan(const unsigned* __restrict__ bcnt,
                                               unsigned* __restrict__ bbase,
                                               unsigned* __restrict__ bcur,
                                               int* __restrict__ rowptr,
                                               int P, int N, int E) {
  __shared__ unsigned wsum[4];
  int tid = threadIdx.x;
  unsigned v = (tid < P) ? bcnt[tid] : 0u;
  unsigned sv = v;
#pragma unroll
  for (int off = 1; off < 64; off <<= 1) {
    unsigned t = __shfl_up(sv, off);
    if ((tid & 63) >= off) sv += t;
  }
  int w = tid >> 6;
  if ((tid & 63) == 63) wsum[w] = sv;
  __syncthreads();
  unsigned wpre = 0;
  for (int k = 0; k < w; ++k) wpre += wsum[k];
  unsigned excl = wpre + sv - v;
  if (tid < P) {
    bbase[tid] = excl;
    bcur[tid] = excl;
  }
  if (tid == P - 1) bbase[P] = excl + v;
  if (tid == 0) rowptr[N] = E;
}

// binning pass 2: reserve ranges using precomputed per-block hist, write packed
// packed = src | (dst&255)<<16
__global__ __launch_bounds__(256) void k_binscat(const int* __restrict__ src,
                                                 const int* __restrict__ dst,
                                                 const unsigned* __restrict__ bhist,
                                                 unsigned* __restrict__ bcur,
                                                 unsigned* __restrict__ packed, int E) {
  __shared__ unsigned hist[256];
  __shared__ unsigned basel[256];
  int tid = threadIdx.x;
  unsigned c = bhist[blockIdx.x * 256 + tid];
  if (c) basel[tid] = atomicAdd(&bcur[tid], c);
  hist[tid] = 0u;
  __syncthreads();
  int i0 = blockIdx.x * ECHUNK;
  int i1 = min(i0 + ECHUNK, E);
  for (int i = i0 + tid; i < i1; i += 256) {
    unsigned d = (unsigned)dst[i];
    unsigned b = d >> 8;
    unsigned pos = basel[b] + atomicAdd(&hist[b], 1u);
    packed[pos] = ((unsigned)src[i]) | ((d & 255u) << 16);
  }
}

// per-bucket CSR finalize: dinv + rowptr (coalesced), esrc (LDS-cursor scatter)
__global__ __launch_bounds__(256) void k_bcsr(const unsigned* __restrict__ packed,
                                              const unsigned* __restrict__ bbase,
                                              float* __restrict__ dinv,
                                              int* __restrict__ rowptr,
                                              int* __restrict__ esrc, int N) {
  __shared__ unsigned hist[256];
  __shared__ unsigned rowloc[256];
  __shared__ unsigned cur[256];
  __shared__ unsigned wsum[4];
  int tid = threadIdx.x, b = blockIdx.x;
  int e0 = (int)bbase[b], e1 = (int)bbase[b + 1];
  hist[tid] = 0u;
  __syncthreads();
  for (int i = e0 + tid; i < e1; i += 256)
    atomicAdd(&hist[packed[i] >> 16], 1u);
  __syncthreads();
  unsigned v = hist[tid];
  unsigned sv = v;
#pragma unroll
  for (int off = 1; off < 64; off <<= 1) {
    unsigned t = __shfl_up(sv, off);
    if ((tid & 63) >= off) sv += t;
  }
  int w = tid >> 6;
  if ((tid & 63) == 63) wsum[w] = sv;
  __syncthreads();
  unsigned wpre = 0;
  for (int k = 0; k < w; ++k) wpre += wsum[k];
  unsigned excl = wpre + sv - v;
  int node = b * 256 + tid;
  if (node < N) {
    dinv[node] = rsqrtf((float)v + 1.0f);  // +1 = self-loop
    rowptr[node] = e0 + (int)excl;
  }
  rowloc[tid] = (unsigned)e0 + excl;
  cur[tid] = 0u;
  __syncthreads();
  for (int i = e0 + tid; i < e1; i += 256) {
    unsigned pk = packed[i];
    unsigned dl = pk >> 16;
    unsigned pos = rowloc[dl] + atomicAdd(&cur[dl], 1u);
    esrc[pos] = (int)(pk & 0xffffu);
  }
}

// fused conversions: blocks [0,128) W1->w1t, [128,256) W2->w2t, rest x->xh
__global__ __launch_bounds__(256) void k_prep(const float* __restrict__ W1,
                                              const float* __restrict__ W2,
                                              const float* __restrict__ x,
                                              _Float16* __restrict__ w1t,
                                              _Float16* __restrict__ w2t,
                                              _Float16* __restrict__ xh, int n4) {
  int b = blockIdx.x;
  if (b < 128) {  // W1 [F][HID] -> w1t [HID][F]
    int idx = b * 256 + threadIdx.x;
    int k = idx / HID, n = idx - k * HID;
    w1t[n * F + k] = (_Float16)W1[idx];
  } else if (b < 256) {  // W2 [HID][F] -> w2t [F][HID]
    int idx = (b - 128) * 256 + threadIdx.x;
    int k = idx / F, n = idx - k * F;
    w2t[n * HID + k] = (_Float16)W2[idx];
  } else {  // x fp32 -> f16 plane
    int i = (b - 256) * 256 + threadIdx.x;
    if (i < n4) {
      float4 v = ((const float4*)x)[i];
      f16x4 o;
      o.x = (_Float16)v.x; o.y = (_Float16)v.y;
      o.z = (_Float16)v.z; o.w = (_Float16)v.w;
      ((f16x4*)xh)[i] = o;
    }
  }
}

// Layer-1 agg: dual-row gather of f16 x rows; lanes<32 row j, lanes>=32 row j+1.
// Each lane: f16x4 (8B) of features [4*li..4*li+3]. Combine via shfl_xor(32).
__global__ __launch_bounds__(256) void k_agg1(const int* __restrict__ rowptr,
                                              const int* __restrict__ esrc,
                                              const float* __restrict__ dinv,
                                              const _Float16* __restrict__ xh,
                                              _Float16* __restrict__ outp, int N) {
  int node = blockIdx.x * 4 + (threadIdx.x >> 6);
  int lane = threadIdx.x & 63;
  int li = lane & 31, hi = lane >> 5;
  if (node >= N) return;
  float di = dinv[node];
  float w0 = di * di;
  f16x4 sv = ((const f16x4*)(xh + (size_t)node * F))[li];
  float4 acc = make_float4(0.f, 0.f, 0.f, 0.f);
  int beg = rowptr[node], end = rowptr[node + 1];
  for (int b = beg; b < end; b += 64) {
    int n = min(64, end - b);
    int s = 0;
    float w = 0.f;
    if (lane < n) {
      s = esrc[b + lane];
      w = dinv[s] * di;
    }
    int t = 0;
    for (; t + 15 < n; t += 16) {  // 8 pairs = 16 rows in flight
      int ss[8];
      float wz[8];
#pragma unroll
      for (int j = 0; j < 8; ++j) {
        int idx = t + 2 * j + hi;
        ss[j] = __shfl(s, idx);
        wz[j] = __shfl(w, idx);
      }
      f16x4 vv[8];
#pragma unroll
      for (int j = 0; j < 8; ++j)
        vv[j] = ((const f16x4*)(xh + (size_t)ss[j] * F))[li];
#pragma unroll
      for (int j = 0; j < 8; ++j) {
        acc.x += (float)vv[j].x * wz[j];
        acc.y += (float)vv[j].y * wz[j];
        acc.z += (float)vv[j].z * wz[j];
        acc.w += (float)vv[j].w * wz[j];
      }
    }
    for (; t < n; t += 2) {  // pair tail; idx==n lanes have w=0 (safe)
      int idx = t + hi;
      int s0 = __shfl(s, idx);
      float wa = __shfl(w, idx);
      f16x4 v0 = ((const f16x4*)(xh + (size_t)s0 * F))[li];
      acc.x += (float)v0.x * wa;
      acc.y += (float)v0.y * wa;
      acc.z += (float)v0.z * wa;
      acc.w += (float)v0.w * wa;
    }
  }
  acc.x += __shfl_xor(acc.x, 32);
  acc.y += __shfl_xor(acc.y, 32);
  acc.z += __shfl_xor(acc.z, 32);
  acc.w += __shfl_xor(acc.w, 32);
  if (hi == 0) {
    f16x4 ov;
    ov.x = (_Float16)(acc.x + (float)sv.x * w0);
    ov.y = (_Float16)(acc.y + (float)sv.y * w0);
    ov.z = (_Float16)(acc.z + (float)sv.z * w0);
    ov.w = (_Float16)(acc.w + (float)sv.w * w0);
    ((f16x4*)(outp + (size_t)node * F))[li] = ov;
  }
}

// Layer-2 agg: dual-row gather of f16 h2 rows + bias -> fp32 out (final)
__global__ __launch_bounds__(256) void k_agg_out(const int* __restrict__ rowptr,
                                                 const int* __restrict__ esrc,
                                                 const float* __restrict__ dinv,
                                                 const _Float16* __restrict__ hb,
                                                 const float* __restrict__ bias,
                                                 float* __restrict__ outp, int N) {
  int node = blockIdx.x * 4 + (threadIdx.x >> 6);
  int lane = threadIdx.x & 63;
  int li = lane & 31, hi = lane >> 5;
  if (node >= N) return;
  float di = dinv[node];
  float w0 = di * di;
  f16x4 sv = ((const f16x4*)(hb + (size_t)node * F))[li];
  float4 acc = make_float4(0.f, 0.f, 0.f, 0.f);
  int beg = rowptr[node], end = rowptr[node + 1];
  for (int b = beg; b < end; b += 64) {
    int n = min(64, end - b);
    int s = 0;
    float w = 0.f;
    if (lane < n) {
      s = esrc[b + lane];
      w = dinv[s] * di;
    }
    int t = 0;
    for (; t + 15 < n; t += 16) {
      int ss[8];
      float wz[8];
#pragma unroll
      for (int j = 0; j < 8; ++j) {
        int idx = t + 2 * j + hi;
        ss[j] = __shfl(s, idx);
        wz[j] = __shfl(w, idx);
      }
      f16x4 vv[8];
#pragma unroll
      for (int j = 0; j < 8; ++j)
        vv[j] = ((const f16x4*)(hb + (size_t)ss[j] * F))[li];
#pragma unroll
      for (int j = 0; j < 8; ++j) {
        acc.x += (float)vv[j].x * wz[j];
        acc.y += (float)vv[j].y * wz[j];
        acc.z += (float)vv[j].z * wz[j];
        acc.w += (float)vv[j].w * wz[j];
      }
    }
    for (; t < n; t += 2) {
      int idx = t + hi;
      int s0 = __shfl(s, idx);
      float wa = __shfl(w, idx);
      f16x4 v0 = ((const f16x4*)(hb + (size_t)s0 * F))[li];
      acc.x += (float)v0.x * wa;
      acc.y += (float)v0.y * wa;
      acc.z += (float)v0.z * wa;
      acc.w += (float)v0.w * wa;
    }
  }
  acc.x += __shfl_xor(acc.x, 32);
  acc.y += __shfl_xor(acc.y, 32);
  acc.z += __shfl_xor(acc.z, 32);
  acc.w += __shfl_xor(acc.w, 32);
  if (hi == 0) {
    float4 bb = ((const float4*)bias)[li];
    float4 ov;
    ov.x = acc.x + (float)sv.x * w0 + bb.x;
    ov.y = acc.y + (float)sv.y * w0 + bb.y;
    ov.z = acc.z + (float)sv.z * w0 + bb.z;
    ov.w = acc.w + (float)sv.w * w0 + bb.w;
    ((float4*)(outp + (size_t)node * F))[li] = ov;
  }
}

// GEMM1: z1(f16) = relu( A(f16)[M,128] @ W1t(f16)[256,128]^T + b1 )
// block = 64 rows x 256 cols; 4 waves x 64 cols; acc[4][4]; A staged once (16 KB).
__global__ __launch_bounds__(256) void k_gemm1(const _Float16* __restrict__ A,
                                               const _Float16* __restrict__ Bt,
                                               const float* __restrict__ bias,
                                               _Float16* __restrict__ C, int M) {
  __shared__ _Float16 AL[64 * 128];
  int tid = threadIdx.x;
  int lane = tid & 63, wid = tid >> 6;
  int row0 = blockIdx.x * 64;

#pragma unroll
  for (int i = 0; i < 4; ++i) {
    int g = i * 256 + tid;
    int r = g >> 4, gi = g & 15;
    int o = r * 128 + ((gi ^ (r & 7)) * 8);
    size_t go = (size_t)(row0 + r) * 128 + gi * 8;
    *(f16x8*)&AL[o] = *(const f16x8*)&A[go];
  }
  __syncthreads();

  f32x4 acc[4][4] = {};
#pragma unroll
  for (int ks = 0; ks < 4; ++ks) {
    f16x8 ah[4], bh[4];
#pragma unroll
    for (int mf = 0; mf < 4; ++mf) {
      int r = mf * 16 + (lane & 15);
      int g = ks * 4 + (lane >> 4);
      int o = r * 128 + ((g ^ (r & 7)) * 8);
      ah[mf] = *(const f16x8*)&AL[o];
    }
#pragma unroll
    for (int nf = 0; nf < 4; ++nf) {
      int c = wid * 64 + nf * 16 + (lane & 15);
      size_t o = (size_t)c * 128 + ks * 32 + (lane >> 4) * 8;
      bh[nf] = *(const f16x8*)&Bt[o];
    }
#pragma unroll
    for (int mf = 0; mf < 4; ++mf)
#pragma unroll
      for (int nf = 0; nf < 4; ++nf)
        acc[mf][nf] = __builtin_amdgcn_mfma_f32_16x16x32_f16(
            ah[mf], bh[nf], acc[mf][nf], 0, 0, 0);
  }

  // epilogue: D col=lane&15, row=(lane>>4)*4+reg
#pragma unroll
  for (int mf = 0; mf < 4; ++mf) {
    int r0 = row0 + mf * 16 + (lane >> 4) * 4;
#pragma unroll
    for (int nf = 0; nf < 4; ++nf) {
      int c = wid * 64 + nf * 16 + (lane & 15);
      float bv = bias[c];
#pragma unroll
      for (int r = 0; r < 4; ++r) {
        if (r0 + r < M) {
          float v = fmaxf(acc[mf][nf][r] + bv, 0.f);
          C[(size_t)(r0 + r) * HID + c] = (_Float16)v;
        }
      }
    }
  }
}

// GEMM2: h2(f16) = Z(f16)[M,256] @ W2t(f16)[128,256]^T
// block = 64 rows x 128 cols; 4 waves x 32 cols; whole K=256 of Z in LDS (32 KB).
__global__ __launch_bounds__(256) void k_gemm2(const _Float16* __restrict__ Z,
                                               const _Float16* __restrict__ Bt,
                                               _Float16* __restrict__ C, int M) {
  __shared__ _Float16 ZL[64 * 256];
  int tid = threadIdx.x;
  int lane = tid & 63, wid = tid >> 6;
  int row0 = blockIdx.x * 64;

#pragma unroll
  for (int i = 0; i < 8; ++i) {
    int g = i * 256 + tid;
    int r = g >> 5, gi = g & 31;
    int o = r * 256 + ((gi ^ (r & 7)) * 8);
    size_t go = (size_t)(row0 + r) * 256 + gi * 8;
    *(f16x8*)&ZL[o] = *(const f16x8*)&Z[go];
  }
  __syncthreads();

  f32x4 acc[4][2] = {};
#pragma unroll
  for (int ks = 0; ks < 8; ++ks) {
    f16x8 ah[4], bh[2];
#pragma unroll
    for (int mf = 0; mf < 4; ++mf) {
      int r = mf * 16 + (lane & 15);
      int g = ks * 4 + (lane >> 4);
      int o = r * 256 + ((g ^ (r & 7)) * 8);
      ah[mf] = *(const f16x8*)&ZL[o];
    }
#pragma unroll
    for (int nf = 0; nf < 2; ++nf) {
      int c = wid * 32 + nf * 16 + (lane & 15);
      size_t o = (size_t)c * 256 + ks * 32 + (lane >> 4) * 8;
      bh[nf] = *(const f16x8*)&Bt[o];
    }
#pragma unroll
    for (int mf = 0; mf < 4; ++mf)
#pragma unroll
      for (int nf = 0; nf < 2; ++nf)
        acc[mf][nf] = __builtin_amdgcn_mfma_f32_16x16x32_f16(
            ah[mf], bh[nf], acc[mf][nf], 0, 0, 0);
  }

#pragma unroll
  for (int mf = 0; mf < 4; ++mf) {
    int r0 = row0 + mf * 16 + (lane >> 4) * 4;
#pragma unroll
    for (int nf = 0; nf < 2; ++nf) {
      int c = wid * 32 + nf * 16 + (lane & 15);
#pragma unroll
      for (int r = 0; r < 4; ++r)
        if (r0 + r < M) C[(size_t)(r0 + r) * F + c] = (_Float16)acc[mf][nf][r];
    }
  }
}

extern "C" void kernel_launch(void* const* d_in, const int* in_sizes, int n_in,
                              void* d_out, int out_size, void* d_ws, size_t ws_size,
                              hipStream_t stream) {
  const float* x = (const float*)d_in[0];
  const int* ei = (const int*)d_in[1];
  const float* W1 = (const float*)d_in[2];
  const float* b1 = (const float*)d_in[3];
  const float* W2 = (const float*)d_in[4];
  const float* b2 = (const float*)d_in[5];
  float* out = (float*)d_out;

  int N = in_sizes[0] / F;  // 50000
  int E = in_sizes[1] / 2;  // 800000
  const int* src = ei;
  const int* dst = ei + E;
  int P = (N + 255) / 256;  // dst buckets of 256 nodes (N < 65536)
  int nbC = (E + ECHUNK - 1) / ECHUNK;

  // workspace layout (byte-based, 256B aligned chunks)
  char* ws = (char*)d_ws;
  size_t off = 0;
  auto allocB = [&](size_t bytes) {
    void* p = ws + off;
    off += ((bytes + 255) & ~(size_t)255);
    return p;
  };
  float* dinv = (float*)allocB((size_t)N * 4);
  int* rowptr = (int*)allocB(((size_t)N + 1) * 4);
  unsigned* bcnt = (unsigned*)allocB(256 * 4);
  unsigned* bbase = (unsigned*)allocB(257 * 4);
  unsigned* bcur = (unsigned*)allocB(256 * 4);
  unsigned* bhist = (unsigned*)allocB((size_t)nbC * 256 * 4);
  unsigned* packed = (unsigned*)allocB((size_t)E * 4);
  int* esrc = (int*)allocB((size_t)E * 4);
  _Float16* xh = (_Float16*)allocB((size_t)N * F * 2);  // x f16 table
  // +64 row padding so tail-block LDS staging reads stay in-bounds
  _Float16* agg = (_Float16*)allocB((size_t)(N + 64) * F * 2);
  _Float16* z1 = (_Float16*)allocB((size_t)(N + 64) * HID * 2);
  _Float16* w1t = (_Float16*)allocB((size_t)F * HID * 2);
  _Float16* w2t = (_Float16*)allocB((size_t)HID * F * 2);
  // h2 f16 (12.8MB) reuses the agg plane (dead after GEMM1)
  _Float16* h2 = agg;

  int n4 = N * F / 4;
  int nbPrep = 256 + (n4 + 255) / 256;

  k_prep<<<nbPrep, 256, 0, stream>>>(W1, W2, x, w1t, w2t, xh, n4);

  // CSR build via bucketed counting sort
  hipMemsetAsync(bcnt, 0, 256 * 4, stream);
  k_binc<<<nbC, 256, 0, stream>>>(dst, bcnt, bhist, E);
  k_bscan<<<1, 256, 0, stream>>>(bcnt, bbase, bcur, rowptr, P, N, E);
  k_binscat<<<nbC, 256, 0, stream>>>(src, dst, bhist, bcur, packed, E);
  k_bcsr<<<P, 256, 0, stream>>>(packed, bbase, dinv, rowptr, esrc, N);

  int nbAgg = (N + 3) / 4;
  int mb = (N + 63) / 64;

  // layer 1: agg(f16) = A x  (dual-row f16 gather) ; z1 = relu(agg @ W1 + b1)
  k_agg1<<<nbAgg, 256, 0, stream>>>(rowptr, esrc, dinv, xh, agg, N);
  k_gemm1<<<mb, 256, 0, stream>>>(agg, w1t, b1, z1, N);

  // layer 2: h2(f16) = z1 @ W2 ; out = b2 + A h2  (dual-row f16 gather)
  k_gemm2<<<mb, 256, 0, stream>>>(z1, w2t, h2, N);
  k_agg_out<<<nbAgg, 256, 0, stream>>>(rowptr, esrc, dinv, h2, b2, out, N);
}